// Round 4
// baseline (4850.725 us; speedup 1.0000x reference)
//
#include <hip/hip_runtime.h>
#include <math.h>

// OptNet batched QP IPM solver — Round 4.
// One 512-thread block per batch element; 2 blocks/CU (LDS 80992 B <= 81920).
// R and Q^{-1} live in REGISTERS (R tile == chol tile mapping), rank-4 blocked
// register Cholesky (33 barriers), W stride 130 (2-way LDS conflicts = free),
// trtri with packed diag inverses, corrector solve accumulates in place.
// Round 4 fix: __launch_bounds__(512, 2) — (512, 4) forced a 64-VGPR cap and
// spilled ~4 GB to scratch (R3 counters: VGPR=64, hbm_bytes 4.1e9). 128 VGPRs
// is the sweet spot: no spill (R2) and LDS already limits us to 2 blocks/CU.

#define NT  512
#define WST 130    // factor/V stride: 130 % 32 = 2 -> 2-way column conflicts (free)
#define T1O 4352   // t1 = V_Q^T G^T (64 x 128) offset inside W
#define T1S 132
#define GCO 12800  // G^T staging chunk offset inside W
#define GCS 132

struct __align__(16) Smem {
  float W[16640];     // 66560 B: factor/V (128 x WST) | prefactor: V_Q(68) + t1 + G^T chunk
  float Vd[1088];     // packed trtri diag inverses (8x136) / split-k scratch (<=512)
  float pr[1024];     // chol pivot panel, double-buffered 2 x (4 x 128)
  float x[64], rxv[64], g1[64], t[64], dxa[64];
  float s[128], z[128], rz[128], dsa[128], dza[128], u12[128], dd[128], H[128], Y[128];
  float scalbuf[8];   // chol inv-diag, double-buffered 2 x 4
  float scal[16];
};
static_assert(sizeof(Smem) <= 81920, "LDS must fit 2 blocks/CU");

enum { SC_D0 = 0, SC_D1 = 1, SC_H1 = 2, SC_U11I = 4, SC_RY = 5, SC_MU = 6,
       SC_ALPHA = 7, SC_MUSIG = 8, SC_Y = 9, SC_DYA = 10, SC_WY = 11,
       SC_MINS = 12, SC_MINZ = 13 };

__device__ __forceinline__ float wred_sum(float v) {
#pragma unroll
  for (int off = 32; off > 0; off >>= 1) v += __shfl_down(v, off);
  return v;
}
__device__ __forceinline__ float wred_min(float v) {
#pragma unroll
  for (int off = 32; off > 0; off >>= 1) v = fminf(v, __shfl_down(v, off));
  return v;
}
__device__ __forceinline__ float step_val(float v, float dv) {
  float a = -v / dv;
  return (a > 0.0f) ? a : __builtin_inff();  // NaN -> inf (matches ref)
}
__device__ __forceinline__ constexpr int pk16(int i) {  // packed 16x16 upper row start
  return i * 16 - ((i * (i - 1)) >> 1);
}

// ---- LDS chol, 1 barrier/column (only for the cheap 64x64 Q pre-factor) ----
__device__ void chol_ldl(float* W, int n, int st, float* dinv2, int tid) {
  if (tid == 0) dinv2[SC_D0] = 1.0f / W[0];
  __syncthreads();
  for (int k = 0; k < n - 1; ++k) {
    const float invd = dinv2[k & 1];
    const int row = k + 1 + (tid >> 1);
    if (row < n) {
      const float m = W[k * st + row] * invd;
      for (int j = row + (tid & 1); j < n; j += 2)
        W[row * st + j] -= m * W[k * st + j];
      if (tid == 0) dinv2[(k + 1) & 1] = 1.0f / W[row * st + row];
    }
    __syncthreads();
  }
  for (int k = tid; k < n; k += NT) {
    const float rd = 1.0f / sqrtf(W[k * st + k]);
    for (int j = k; j < n; ++j) W[k * st + j] *= rd;
  }
  __syncthreads();
}

// ---- trtri for the 64x64 Q factor (uses Vd as 4 full 16x16 blocks) ----
__device__ void trtri_small(float* W, int n, int st, float* Vd, int tid) {
  const int nblk = n >> 4;
  if (tid < nblk * 16) {
    const int blk = tid >> 4, c = tid & 15;
    const float* D = W + (16 * blk) * st + 16 * blk;
    float vv[16];
#pragma unroll
    for (int i = 15; i >= 0; --i) {
      float acc = 0.0f;
      for (int k = i + 1; k < 16; ++k) acc += D[i * st + k] * vv[k];
      const float di = D[i * st + i];
      const float val = (i == c) ? (1.0f / di) : (-acc / di);
      vv[i] = (i <= c) ? val : 0.0f;
    }
#pragma unroll
    for (int i = 0; i < 16; ++i) Vd[blk * 256 + i * 16 + c] = vv[i];
  }
  __syncthreads();
  for (int J = 0; J < nblk; ++J) {
    const int Jb = 16 * J;
    if (tid < Jb) {
      const int k = tid;
      float u[16], o[16];
#pragma unroll
      for (int jj = 0; jj < 16; ++jj) u[jj] = W[k * st + Jb + jj];
#pragma unroll
      for (int c = 0; c < 16; ++c) {
        float acc = 0.0f;
#pragma unroll
        for (int jj = 0; jj <= c; ++jj) acc += u[jj] * Vd[J * 256 + jj * 16 + c];
        o[c] = acc;
      }
#pragma unroll
      for (int c = 0; c < 16; ++c) W[k * st + Jb + c] = o[c];
    }
    __syncthreads();
    const int nOff = Jb * 16;
    const int nTot = nOff + 256;
    float rbuf[2];
    int cnt = 0;
    for (int id = tid; id < nTot; id += NT) {
      float val;
      if (id < nOff) {
        const int i = id >> 4, c = id & 15;
        float acc = 0.0f;
        for (int k = i; k < Jb; ++k) acc += W[i * st + k] * W[k * st + Jb + c];
        val = -acc;
      } else {
        val = Vd[J * 256 + (id - nOff)];
      }
      rbuf[cnt++] = val;
    }
    __syncthreads();
    cnt = 0;
    for (int id = tid; id < nTot; id += NT) {
      int i, c;
      if (id < nOff) { i = id >> 4; c = id & 15; }
      else { const int l = id - nOff; i = Jb + (l >> 4); c = l & 15; }
      W[i * st + Jb + c] = rbuf[cnt++];
    }
    __syncthreads();
  }
}

// ---- trtri for the 128 factor at stride WST, packed diag inverses in Vd ----
__device__ void trtri128(Smem& sm, int tid) {
  if (tid < 128) {  // invert 16x16 diag blocks -> packed Vd (136/block)
    const int blk = tid >> 4, c = tid & 15;
    const float* D = sm.W + (blk << 4) * WST + (blk << 4);
    float vv[16];
#pragma unroll
    for (int i = 15; i >= 0; --i) {
      float acc = 0.0f;
      for (int k = i + 1; k < 16; ++k) acc += D[i * WST + k] * vv[k];
      const float di = D[i * WST + i];
      const float val = (i == c) ? (1.0f / di) : (-acc / di);
      vv[i] = (i <= c) ? val : 0.0f;
    }
#pragma unroll
    for (int i = 0; i < 16; ++i)
      if (i <= c) sm.Vd[blk * 136 + pk16(i) + (c - i)] = vv[i];
  }
  __syncthreads();
  for (int J = 0; J < 8; ++J) {
    const int Jb = J << 4;
    if (J > 0) {
      if (tid < Jb) {  // stage A: U' = U[0:Jb, Jblk] * Vd[J]  (float2: rows 8B-aligned)
        float u[16], o[16];
        float2* wr = (float2*)&sm.W[tid * WST + Jb];
#pragma unroll
        for (int q = 0; q < 8; ++q) { const float2 v = wr[q]; u[2*q] = v.x; u[2*q+1] = v.y; }
        const float* vd = sm.Vd + J * 136;
#pragma unroll
        for (int c = 0; c < 16; ++c) {
          float acc = 0.0f;
#pragma unroll
          for (int jj = 0; jj <= c; ++jj) acc += u[jj] * vd[pk16(jj) + (c - jj)];
          o[c] = acc;
        }
#pragma unroll
        for (int q = 0; q < 8; ++q) wr[q] = make_float2(o[2*q], o[2*q+1]);
      }
      __syncthreads();
    }
    // stage B: M = -V[:,0:Jb] * U'  (1-row x 4-col strips) + diag-block copy
    const int nStrip = Jb << 2;
    float acc[4] = {0.0f, 0.0f, 0.0f, 0.0f};
    int wi = 0, wc = 0;
    if (tid < nStrip) {
      wi = tid >> 2; wc = (tid & 3) << 2;
      for (int k = wi; k < Jb; ++k) {
        const float v = sm.W[wi * WST + k];
        const float2 u0 = *(const float2*)&sm.W[k * WST + Jb + wc];
        const float2 u1 = *(const float2*)&sm.W[k * WST + Jb + wc + 2];
        acc[0] = fmaf(v, u0.x, acc[0]); acc[1] = fmaf(v, u0.y, acc[1]);
        acc[2] = fmaf(v, u1.x, acc[2]); acc[3] = fmaf(v, u1.y, acc[3]);
      }
      acc[0] = -acc[0]; acc[1] = -acc[1]; acc[2] = -acc[2]; acc[3] = -acc[3];
    } else if (tid < nStrip + 64) {
      const int l = tid - nStrip;
      const int r = l >> 2; wi = Jb + r; wc = (l & 3) << 2;
      const float* vp = sm.Vd + J * 136 + pk16(r) - r;
#pragma unroll
      for (int q = 0; q < 4; ++q) {
        const int c = wc + q;
        acc[q] = (c >= r) ? vp[c] : 0.0f;
      }
    }
    __syncthreads();
    if (tid < nStrip + 64) {
      *(float2*)&sm.W[wi * WST + Jb + wc]     = make_float2(acc[0], acc[1]);
      *(float2*)&sm.W[wi * WST + Jb + wc + 2] = make_float2(acc[2], acc[3]);
    }
    __syncthreads();
  }
}

// ---- owner-group elimination of 4 pivot rows + panel publish (phase q) ----
__device__ __forceinline__ void elim_publish(Smem& sm, float (&Wt)[4][8],
                                             float (&sq)[4], int q, int tc) {
  const int tcd = q >> 1;          // thread column holding the 4x4 diag block
  const int co = (q & 1) << 2;     // its column offset within the 8-col tile
  float L10 = 0, L20 = 0, L30 = 0, L21 = 0, L31 = 0, L32 = 0;
  float id0 = 0, id1 = 0, id2 = 0, id3 = 0;
  if (tc == tcd) {  // local LDL elimination of the 4x4 diag block
    float D[4][4];
#pragma unroll
    for (int m = 0; m < 4; ++m)
#pragma unroll
      for (int c = 0; c < 4; ++c) D[m][c] = Wt[m][co + c];
    id0 = 1.0f / D[0][0];
    L10 = D[0][1] * id0; L20 = D[0][2] * id0; L30 = D[0][3] * id0;
#pragma unroll
    for (int c = 0; c < 4; ++c) {
      D[1][c] -= L10 * D[0][c]; D[2][c] -= L20 * D[0][c]; D[3][c] -= L30 * D[0][c];
    }
    id1 = 1.0f / D[1][1];
    L21 = D[1][2] * id1; L31 = D[1][3] * id1;
#pragma unroll
    for (int c = 0; c < 4; ++c) { D[2][c] -= L21 * D[1][c]; D[3][c] -= L31 * D[1][c]; }
    id2 = 1.0f / D[2][2];
    L32 = D[2][3] * id2;
#pragma unroll
    for (int c = 0; c < 4; ++c) D[3][c] -= L32 * D[2][c];
    id3 = 1.0f / D[3][3];
  }
  const int src = ((q & 3) << 4) + tcd;  // wave-local lane of tcd in the owner group
  L10 = __shfl(L10, src); L20 = __shfl(L20, src); L30 = __shfl(L30, src);
  L21 = __shfl(L21, src); L31 = __shfl(L31, src); L32 = __shfl(L32, src);
  id0 = __shfl(id0, src); id1 = __shfl(id1, src);
  id2 = __shfl(id2, src); id3 = __shfl(id3, src);
#pragma unroll
  for (int c = 0; c < 8; ++c) {  // apply (sequenced) elimination to own 8 cols
    Wt[1][c] = fmaf(-L10, Wt[0][c], Wt[1][c]);
    Wt[2][c] = fmaf(-L20, Wt[0][c], Wt[2][c]);
    Wt[2][c] = fmaf(-L21, Wt[1][c], Wt[2][c]);
    Wt[3][c] = fmaf(-L30, Wt[0][c], Wt[3][c]);
    Wt[3][c] = fmaf(-L31, Wt[1][c], Wt[3][c]);
    Wt[3][c] = fmaf(-L32, Wt[2][c], Wt[3][c]);
  }
  sq[0] = sqrtf(id0); sq[1] = sqrtf(id1); sq[2] = sqrtf(id2); sq[3] = sqrtf(id3);
  const int nb = q & 1;
  float* pp = sm.pr + nb * 512;
  const int j0 = tc << 3;
#pragma unroll
  for (int m = 0; m < 4; ++m) {
    *(float4*)&pp[m * 128 + j0]     = make_float4(Wt[m][0], Wt[m][1], Wt[m][2], Wt[m][3]);
    *(float4*)&pp[m * 128 + j0 + 4] = make_float4(Wt[m][4], Wt[m][5], Wt[m][6], Wt[m][7]);
  }
  if (tc == tcd) {
    sm.scalbuf[nb * 4 + 0] = id0; sm.scalbuf[nb * 4 + 1] = id1;
    sm.scalbuf[nb * 4 + 2] = id2; sm.scalbuf[nb * 4 + 3] = id3;
  }
}

// ---- rank-4 blocked register Cholesky of S = R + diag + eps, then V = U^{-1} ----
__device__ void factor_S(Smem& sm, const float (&racc)[4][8], int init, int tid) {
  const int tr = tid >> 4, tc = tid & 15;
  const int i0 = tr << 2, j0 = tc << 3;
  float Wt[4][8];
  float sq[4] = {0, 0, 0, 0};
#pragma unroll
  for (int m = 0; m < 4; ++m) {
    const int i = i0 + m;
#pragma unroll
    for (int c = 0; c < 8; ++c) {
      float v = racc[m][c];
      if (i == j0 + c) v += (init ? 1.0f : sm.s[i] / sm.z[i]) + 1e-6f;
      Wt[m][c] = v;
    }
  }
  if (tr == 0) elim_publish(sm, Wt, sq, 0, tc);
  __syncthreads();
  for (int p = 0; p <= 30; ++p) {
    const int pb = p & 1;
    if (tr > p) {
      const float* pp = sm.pr + pb * 512;
      const float id_0 = sm.scalbuf[pb * 4 + 0], id_1 = sm.scalbuf[pb * 4 + 1];
      const float id_2 = sm.scalbuf[pb * 4 + 2], id_3 = sm.scalbuf[pb * 4 + 3];
      const float idv[4] = {id_0, id_1, id_2, id_3};
#pragma unroll
      for (int mm = 0; mm < 4; ++mm) {  // branchless rank-4 update; garbage lands
        const float4 pv  = *(const float4*)&pp[mm * 128 + i0];   // strictly-lower only
        const float4 pj0 = *(const float4*)&pp[mm * 128 + j0];
        const float4 pj1 = *(const float4*)&pp[mm * 128 + j0 + 4];
        const float um0 = pv.x * idv[mm], um1 = pv.y * idv[mm];
        const float um2 = pv.z * idv[mm], um3 = pv.w * idv[mm];
        const float pjv[8] = {pj0.x, pj0.y, pj0.z, pj0.w, pj1.x, pj1.y, pj1.z, pj1.w};
#pragma unroll
        for (int c = 0; c < 8; ++c) {
          Wt[0][c] = fmaf(-um0, pjv[c], Wt[0][c]);
          Wt[1][c] = fmaf(-um1, pjv[c], Wt[1][c]);
          Wt[2][c] = fmaf(-um2, pjv[c], Wt[2][c]);
          Wt[3][c] = fmaf(-um3, pjv[c], Wt[3][c]);
        }
      }
      if (tr == p + 1) elim_publish(sm, Wt, sq, p + 1, tc);
    }
    __syncthreads();
  }
#pragma unroll
  for (int m = 0; m < 4; ++m) {  // write U (sqrt-scaled) to W, stride WST
#pragma unroll
    for (int qq = 0; qq < 4; ++qq)
      *(float2*)&sm.W[(i0 + m) * WST + j0 + 2 * qq] =
          make_float2(Wt[m][2 * qq] * sq[m], Wt[m][2 * qq + 1] * sq[m]);
  }
  __syncthreads();
  trtri128(sm, tid);
}

// ---- KKT solve: matvecs only. qreg = this thread's 8 Q^{-1} values. ----
__device__ void solve_kkt(Smem& sm, const float* qreg, const float* Gb, const float* Ab,
                          int has_rx, const float* rx, const float* rs,
                          int has_rz, const float* rz, float ry,
                          float* dx_t, float* ds_t, float* dz_t, int dy_slot,
                          int accum, int tid) {
  const float u11i = sm.scal[SC_U11I];
  const int o8 = tid >> 3, seg = tid & 7;
  if (has_rx) {  // t = Qinv rx via register Qi + 8-lane shfl reduce
    float acc = 0.0f;
#pragma unroll
    for (int c = 0; c < 8; ++c) acc += qreg[c] * rx[seg * 8 + c];
    acc += __shfl_down(acc, 4); acc += __shfl_down(acc, 2); acc += __shfl_down(acc, 1);
    if (seg == 0) sm.t[o8] = acc;
    __syncthreads();
  }
  {  // H = G t + rs/d - rz  (coalesced float4 row dots, 4-lane groups)
    const int i = tid >> 2, q = tid & 3;
    float acc = 0.0f;
    if (has_rx) {
      const float* gr = Gb + (i << 6) + (q << 4);
#pragma unroll
      for (int kk = 0; kk < 16; kk += 4) {
        const float4 g4 = *(const float4*)(gr + kk);
        const float4 t4 = *(const float4*)&sm.t[(q << 4) + kk];
        acc += g4.x * t4.x + g4.y * t4.y + g4.z * t4.z + g4.w * t4.w;
      }
    }
    acc += __shfl_down(acc, 2); acc += __shfl_down(acc, 1);
    if (q == 0) {
      if (rs) acc += rs[i] / sm.dd[i];
      if (has_rz) acc -= rz[i];
      sm.H[i] = acc;
    }
  }
  __syncthreads();
  if (tid < 64) {  // H1 = a.t - ry
    float v = has_rx ? (Ab[tid] * sm.t[tid]) : 0.0f;
    v = wred_sum(v);
    if (tid == 0) sm.scal[SC_H1] = v - ry;
  }
  __syncthreads();
  const float y1 = sm.scal[SC_H1] * u11i;
  {  // Y = V^T (H - u12 y1), 4-way split-k, fused adjust
    const int o = tid & 127, p = tid >> 7;
    const int k0 = p << 5;
    int k1 = k0 + 32; if (k1 > o + 1) k1 = o + 1;
    float acc = 0.0f;
    for (int k = k0; k < k1; ++k)
      acc += sm.W[k * WST + o] * (sm.H[k] - sm.u12[k] * y1);
    sm.Vd[(p << 7) + o] = acc;
  }
  __syncthreads();
  if (tid < 128) sm.Y[tid] = sm.Vd[tid] + sm.Vd[128 + tid] + sm.Vd[256 + tid] + sm.Vd[384 + tid];
  __syncthreads();
  {  // wz = -(V Y), 4-way split-k (stride-130 column reads: 2-way = free)
    const int o = tid & 127, p = tid >> 7;
    int k0 = p << 5; if (k0 < o) k0 = o;
    const int k1 = (p << 5) + 32;
    float acc = 0.0f;
    for (int k = k0; k < k1; ++k) acc += sm.W[o * WST + k] * sm.Y[k];
    sm.Vd[(p << 7) + o] = acc;
  }
  __syncthreads();
  if (tid < 128)  // wz lands in H (H is dead after Y)
    sm.H[tid] = -(sm.Vd[tid] + sm.Vd[128 + tid] + sm.Vd[256 + tid] + sm.Vd[384 + tid]);
  __syncthreads();
  if (tid < 64) {  // w_y
    float v = sm.u12[tid] * sm.H[tid] + sm.u12[tid + 64] * sm.H[tid + 64];
    v = wred_sum(v);
    if (tid == 0) {
      const float wy = -(y1 + v) * u11i;
      if (accum) sm.scal[dy_slot] += wy; else sm.scal[dy_slot] = wy;
      sm.scal[SC_WY] = wy;
    }
  }
  __syncthreads();
  const float wy = sm.scal[SC_WY];
  if (tid < 256) {  // g1 partials: -G^T wz (coalesced column reads)
    const int o = tid & 63, p = tid >> 6;
    float acc = 0.0f;
    for (int i = (p << 5); i < (p << 5) + 32; ++i) acc -= Gb[(i << 6) + o] * sm.H[i];
    sm.Vd[(p << 6) + o] = acc;
  } else if (tid < 384) {  // ds = (-rs - wz)/d ; dz = wz  (accumulate for corrector)
    const int i = tid - 256;
    const float wzv = sm.H[i];
    const float r = rs ? rs[i] : 0.0f;
    const float dsv = (-r - wzv) / sm.dd[i];
    if (accum) { ds_t[i] += dsv; dz_t[i] += wzv; }
    else       { ds_t[i] = dsv;  dz_t[i] = wzv; }
  }
  __syncthreads();
  if (tid < 64) {
    float acc = sm.Vd[tid] + sm.Vd[64 + tid] + sm.Vd[128 + tid] + sm.Vd[192 + tid]
              - Ab[tid] * wy;
    if (has_rx) acc -= rx[tid];
    sm.g1[tid] = acc;
  }
  __syncthreads();
  {  // dx = Qinv g1 via register Qi
    float acc = 0.0f;
#pragma unroll
    for (int c = 0; c < 8; ++c) acc += qreg[c] * sm.g1[seg * 8 + c];
    acc += __shfl_down(acc, 4); acc += __shfl_down(acc, 2); acc += __shfl_down(acc, 1);
    if (seg == 0) { if (accum) dx_t[o8] += acc; else dx_t[o8] = acc; }
  }
  __syncthreads();
}

__global__ __launch_bounds__(NT, 2)
void optnet_kernel(const float* __restrict__ Qg, const float* __restrict__ pg,
                   const float* __restrict__ Ag, const float* __restrict__ bg,
                   const float* __restrict__ Gg, const float* __restrict__ hg,
                   float* __restrict__ outg) {
  __shared__ Smem sm;
  const int bId = blockIdx.x;
  const int tid = threadIdx.x;
  const float* Qb = Qg + (size_t)bId * 4096;
  const float* pb = pg + (size_t)bId * 64;
  const float* Ab = Ag + (size_t)bId * 64;
  const float  bb = bg[bId];
  const float* Gb = Gg + (size_t)bId * 8192;
  const float* hb = hg + (size_t)bId * 128;

  // ---- pre-factor Q: chol + trtri at stride 68 -> V_Q (upper), zero lower
  for (int idx = tid; idx < 4096; idx += NT)
    sm.W[(idx >> 6) * 68 + (idx & 63)] = Qb[idx];
  if (tid < 128) sm.dd[tid] = 1.0f;
  __syncthreads();
  chol_ldl(sm.W, 64, 68, sm.scal, tid);
  trtri_small(sm.W, 64, 68, sm.Vd, tid);
  for (int idx = tid; idx < 4096; idx += NT) {
    const int i = idx >> 6, j = idx & 63;
    if (i > j) sm.W[i * 68 + j] = 0.0f;
  }
  __syncthreads();
  // ---- Qinv into registers: thread (o8=tid>>3) holds Qi[o8][8*seg .. +8)
  float qreg[8];
  {
    const int o = tid >> 3, sgq = tid & 7;
#pragma unroll
    for (int c = 0; c < 8; ++c) {
      const int j = sgq * 8 + c;
      float acc = 0.0f;
      for (int k = 0; k < 64; ++k) acc += sm.W[o * 68 + k] * sm.W[j * 68 + k];
      qreg[c] = acc;
    }
  }
  // ---- w = V_Q^T a (into t); u11
  if (tid < 64) {
    float acc = 0.0f;
    for (int m = 0; m < 64; ++m) acc += sm.W[m * 68 + tid] * Ab[m];
    sm.t[tid] = acc;
  }
  __syncthreads();
  if (tid < 64) {
    float v = sm.t[tid] * sm.t[tid];
    v = wred_sum(v);
    if (tid == 0) sm.scal[SC_U11I] = 1.0f / sqrtf(v);
  }
  __syncthreads();
  // ---- t1 = V_Q^T G^T (64 x 128) via staged G^T chunks; register 4x4 tiles
  {
    const int kt = tid & 15, jt = tid >> 4;
    const int k0 = kt << 2, j0 = jt << 2;
    float t1a[4][4] = {};
    for (int mc = 0; mc < 64; mc += 16) {
      for (int idx = tid; idx < 2048; idx += NT) {
        const int j = idx >> 4, mm = idx & 15;
        sm.W[GCO + mm * GCS + j] = Gb[j * 64 + mc + mm];
      }
      __syncthreads();
#pragma unroll 4
      for (int mm = 0; mm < 16; ++mm) {
        const float4 v = *(const float4*)&sm.W[(mc + mm) * 68 + k0];
        const float4 g = *(const float4*)&sm.W[GCO + mm * GCS + j0];
        const float vv[4] = {v.x, v.y, v.z, v.w};
        const float gg[4] = {g.x, g.y, g.z, g.w};
#pragma unroll
        for (int a = 0; a < 4; ++a)
#pragma unroll
          for (int b2 = 0; b2 < 4; ++b2) t1a[a][b2] = fmaf(vv[a], gg[b2], t1a[a][b2]);
      }
      __syncthreads();
    }
#pragma unroll
    for (int a = 0; a < 4; ++a)
      *(float4*)&sm.W[T1O + (k0 + a) * T1S + j0] =
          make_float4(t1a[a][0], t1a[a][1], t1a[a][2], t1a[a][3]);
  }
  __syncthreads();
  // ---- u12 = (t1^T w) * u11i  (split-k over 4 groups)
  {
    const int o = tid & 127, p = tid >> 7;
    float acc = 0.0f;
    for (int k = (p << 4); k < (p << 4) + 16; ++k)
      acc += sm.W[T1O + k * T1S + o] * sm.t[k];
    sm.Vd[(p << 7) + o] = acc;
  }
  __syncthreads();
  if (tid < 128)
    sm.u12[tid] = (sm.Vd[tid] + sm.Vd[128 + tid] + sm.Vd[256 + tid] + sm.Vd[384 + tid])
                  * sm.scal[SC_U11I];
  __syncthreads();
  // ---- R = t1^T t1 - u12 u12^T into REGISTERS (4x8 tile == chol tile)
  float racc[4][8];
  {
    const int tr = tid >> 4, tc = tid & 15;
    const int i0 = tr << 2, j0 = tc << 3;
#pragma unroll
    for (int m = 0; m < 4; ++m)
#pragma unroll
      for (int c = 0; c < 8; ++c) racc[m][c] = 0.0f;
    for (int k = 0; k < 64; ++k) {
      const float4 a  = *(const float4*)&sm.W[T1O + k * T1S + i0];
      const float4 b0 = *(const float4*)&sm.W[T1O + k * T1S + j0];
      const float4 b1 = *(const float4*)&sm.W[T1O + k * T1S + j0 + 4];
      const float av[4] = {a.x, a.y, a.z, a.w};
      const float bv[8] = {b0.x, b0.y, b0.z, b0.w, b1.x, b1.y, b1.z, b1.w};
#pragma unroll
      for (int m = 0; m < 4; ++m)
#pragma unroll
        for (int c = 0; c < 8; ++c) racc[m][c] = fmaf(av[m], bv[c], racc[m][c]);
    }
#pragma unroll
    for (int m = 0; m < 4; ++m) {
      const float ui = sm.u12[i0 + m];
#pragma unroll
      for (int c = 0; c < 8; ++c) racc[m][c] -= ui * sm.u12[j0 + c];
    }
  }
  if (tid < 128) sm.rz[tid] = -hb[tid];
  __syncthreads();

  // ---- initial factor + solve (d = 1)
  factor_S(sm, racc, 1, tid);
  solve_kkt(sm, qreg, Gb, Ab, 1, pb, nullptr, 1, sm.rz, -bb,
            sm.x, sm.s, sm.z, SC_Y, 0, tid);
  if (tid < 64) {
    float v = fminf(sm.s[tid], sm.s[tid + 64]);
    v = wred_min(v);
    if (tid == 0) sm.scal[SC_MINS] = v;
  } else if (tid < 128) {
    const int l = tid - 64;
    float v = fminf(sm.z[l], sm.z[l + 64]);
    v = wred_min(v);
    if (l == 0) sm.scal[SC_MINZ] = v;
  }
  __syncthreads();
  if (tid < 128) {
    const float cs = 1.0f - sm.scal[SC_MINS];
    if (cs > 1.0f) sm.s[tid] += cs;
  } else if (tid < 256) {
    const int i = tid - 128;
    const float cz = 1.0f - sm.scal[SC_MINZ];
    if (cz > 1.0f) sm.z[i] += cz;
  }
  __syncthreads();

  // ---- 5 IPM iterations
  for (int it = 0; it < 5; ++it) {
    if (tid < 256) {  // rx partials: G^T z + Q x (coalesced column reads)
      const int o = tid & 63, pq = tid >> 6;
      float acc = 0.0f;
      for (int i = (pq << 5); i < (pq << 5) + 32; ++i) acc += Gb[(i << 6) + o] * sm.z[i];
      for (int k = (pq << 4); k < (pq << 4) + 16; ++k) acc += Qb[(k << 6) + o] * sm.x[k];
      sm.Vd[(pq << 6) + o] = acc;
    } else {  // rz = G x + s - h (coalesced row dots, 2-lane groups)
      const int l = tid - 256, i = l >> 1, q = l & 1;
      const float* gr = Gb + (i << 6) + (q << 5);
      float acc = 0.0f;
#pragma unroll
      for (int kk = 0; kk < 32; kk += 4) {
        const float4 g4 = *(const float4*)(gr + kk);
        const float4 x4 = *(const float4*)&sm.x[(q << 5) + kk];
        acc += g4.x * x4.x + g4.y * x4.y + g4.z * x4.z + g4.w * x4.w;
      }
      acc += __shfl_down(acc, 1);
      if (q == 0) sm.rz[i] = acc + sm.s[i] - hb[i];
    }
    __syncthreads();
    if (tid < 64)
      sm.rxv[tid] = pb[tid] + Ab[tid] * sm.scal[SC_Y]
                  + sm.Vd[tid] + sm.Vd[64 + tid] + sm.Vd[128 + tid] + sm.Vd[192 + tid];
    __syncthreads();
    if (tid < 64) {  // ry
      float v = Ab[tid] * sm.x[tid];
      v = wred_sum(v);
      if (tid == 0) sm.scal[SC_RY] = v - bb;
    } else if (tid < 128) {  // mu
      const int l = tid - 64;
      float v = sm.s[l] * sm.z[l] + sm.s[l + 64] * sm.z[l + 64];
      v = wred_sum(v);
      if (l == 0) sm.scal[SC_MU] = v * (1.0f / 128.0f);
    } else if (tid < 256) {
      const int i = tid - 128;
      sm.dd[i] = sm.z[i] / sm.s[i];
    }
    __syncthreads();
    factor_S(sm, racc, 0, tid);
    // affine predictor (rs = z)
    solve_kkt(sm, qreg, Gb, Ab, 1, sm.rxv, sm.z, 1, sm.rz, sm.scal[SC_RY],
              sm.dxa, sm.dsa, sm.dza, SC_DYA, 0, tid);
    if (tid < 64) {  // alpha_aff
      float m = __builtin_inff();
#pragma unroll
      for (int rep = 0; rep < 2; ++rep) {
        const int i = tid + 64 * rep;
        m = fminf(m, step_val(sm.z[i], sm.dza[i]));
        m = fminf(m, step_val(sm.s[i], sm.dsa[i]));
      }
      m = wred_min(m);
      if (tid == 0) sm.scal[SC_ALPHA] = 0.999f * fminf(m, 1.0f);
    }
    __syncthreads();
    {
      const float alpha = sm.scal[SC_ALPHA];
      if (tid < 64) {  // sigma -> mu_sig
        float v = 0.0f;
#pragma unroll
        for (int rep = 0; rep < 2; ++rep) {
          const int i = tid + 64 * rep;
          v += (sm.s[i] + alpha * sm.dsa[i]) * (sm.z[i] + alpha * sm.dza[i]);
        }
        v = wred_sum(v);
        if (tid == 0) {
          const float mu = sm.scal[SC_MU];
          const float r = v / (mu * 128.0f);
          sm.scal[SC_MUSIG] = -mu * r * r * r;
        }
      }
    }
    __syncthreads();
    if (tid < 128)  // non_zero (uses AFFINE dsa/dza; reuse rz buffer)
      sm.rz[tid] = (sm.scal[SC_MUSIG] + sm.dsa[tid] * sm.dza[tid]) / sm.s[tid];
    __syncthreads();
    // corrector: accumulates into dxa/dsa/dza/SC_DYA
    solve_kkt(sm, qreg, Gb, Ab, 0, nullptr, sm.rz, 0, nullptr, 0.0f,
              sm.dxa, sm.dsa, sm.dza, SC_DYA, 1, tid);
    if (tid < 64) {  // alpha on combined step
      float m = __builtin_inff();
#pragma unroll
      for (int rep = 0; rep < 2; ++rep) {
        const int i = tid + 64 * rep;
        m = fminf(m, step_val(sm.z[i], sm.dza[i]));
        m = fminf(m, step_val(sm.s[i], sm.dsa[i]));
      }
      m = wred_min(m);
      if (tid == 0) sm.scal[SC_ALPHA] = 0.999f * fminf(m, 1.0f);
    }
    __syncthreads();
    {
      const float a2 = sm.scal[SC_ALPHA];
      if (tid < 128) sm.s[tid] += a2 * sm.dsa[tid];
      else if (tid < 256) sm.z[tid - 128] += a2 * sm.dza[tid - 128];
    }
    if (tid < 64) sm.x[tid] += sm.scal[SC_ALPHA] * sm.dxa[tid];
    if (tid == 64) sm.scal[SC_Y] += sm.scal[SC_ALPHA] * sm.scal[SC_DYA];
    __syncthreads();
  }
  if (tid < 64) outg[((size_t)bId << 6) + tid] = sm.x[tid];
}

extern "C" void kernel_launch(void* const* d_in, const int* in_sizes, int n_in,
                              void* d_out, int out_size, void* d_ws, size_t ws_size,
                              hipStream_t stream) {
  (void)n_in; (void)d_ws; (void)ws_size; (void)out_size;
  const float* Q = (const float*)d_in[0];
  const float* p = (const float*)d_in[1];
  const float* A = (const float*)d_in[2];
  const float* b = (const float*)d_in[3];
  const float* G = (const float*)d_in[4];
  const float* h = (const float*)d_in[5];
  const int B = in_sizes[3];  // b has one element per batch
  optnet_kernel<<<B, NT, 0, stream>>>(Q, p, A, b, G, h, (float*)d_out);
}

// Round 6
// 3707.401 us; speedup vs baseline: 1.3084x; 1.3084x over previous
//
#include <hip/hip_runtime.h>
#include <math.h>

// OptNet batched QP IPM solver — Round 5 (resubmitted unchanged after an
// infrastructure failure: "MI355X container failed twice", no kernel signal).
// One 512-thread block per batch element; 2 blocks/CU (LDS 81504 B <= 81920).
// R5 fix: R no longer lives in registers (R3/R4 spilled ~2.5 GB/dispatch to
// scratch: persistent racc[32]+qreg[8]+Wt[32] > 128 VGPRs). R's off-diagonal
// is stored in the STRICTLY-LOWER triangle of W (W[j*WST+i] for i<j) plus
// Rdiag[128] — chol/trtri/solves only touch j>=i cells, so R survives all 6
// factorizations. Chol U-write and trtri diag-copy are guarded to j>=i.
// Rank-4 register chol (33 barriers), W stride 130 (2-way conflicts = free).

#define NT  512
#define WST 130    // factor/V stride: 130 % 32 = 2 -> 2-way column conflicts (free)
#define T1O 4352   // t1 = V_Q^T G^T (64 x 128) offset inside W
#define T1S 132
#define GCO 12800  // G^T staging chunk offset inside W
#define GCS 132

struct __align__(16) Smem {
  float W[16640];     // 66560 B: upper = factor/V; strictly-lower = R (transposed)
  float Vd[1088];     // packed trtri diag inverses (8x136) / split-k scratch (<=512)
  float pr[1024];     // chol pivot panel, double-buffered 2 x (4 x 128)
  float x[64], rxv[64], g1[64], t[64], dxa[64];
  float s[128], z[128], rz[128], dsa[128], dza[128], u12[128], dd[128], H[128], Y[128];
  float Rdiag[128];   // R's diagonal (lower triangle of W can't hold it)
  float scalbuf[8];   // chol inv-diag, double-buffered 2 x 4
  float scal[16];
};
static_assert(sizeof(Smem) <= 81920, "LDS must fit 2 blocks/CU");

enum { SC_D0 = 0, SC_D1 = 1, SC_H1 = 2, SC_U11I = 4, SC_RY = 5, SC_MU = 6,
       SC_ALPHA = 7, SC_MUSIG = 8, SC_Y = 9, SC_DYA = 10, SC_WY = 11,
       SC_MINS = 12, SC_MINZ = 13 };

__device__ __forceinline__ float wred_sum(float v) {
#pragma unroll
  for (int off = 32; off > 0; off >>= 1) v += __shfl_down(v, off);
  return v;
}
__device__ __forceinline__ float wred_min(float v) {
#pragma unroll
  for (int off = 32; off > 0; off >>= 1) v = fminf(v, __shfl_down(v, off));
  return v;
}
__device__ __forceinline__ float step_val(float v, float dv) {
  float a = -v / dv;
  return (a > 0.0f) ? a : __builtin_inff();  // NaN -> inf (matches ref)
}
__device__ __forceinline__ constexpr int pk16(int i) {  // packed 16x16 upper row start
  return i * 16 - ((i * (i - 1)) >> 1);
}

// ---- LDS chol, 1 barrier/column (only for the cheap 64x64 Q pre-factor) ----
__device__ void chol_ldl(float* W, int n, int st, float* dinv2, int tid) {
  if (tid == 0) dinv2[SC_D0] = 1.0f / W[0];
  __syncthreads();
  for (int k = 0; k < n - 1; ++k) {
    const float invd = dinv2[k & 1];
    const int row = k + 1 + (tid >> 1);
    if (row < n) {
      const float m = W[k * st + row] * invd;
      for (int j = row + (tid & 1); j < n; j += 2)
        W[row * st + j] -= m * W[k * st + j];
      if (tid == 0) dinv2[(k + 1) & 1] = 1.0f / W[row * st + row];
    }
    __syncthreads();
  }
  for (int k = tid; k < n; k += NT) {
    const float rd = 1.0f / sqrtf(W[k * st + k]);
    for (int j = k; j < n; ++j) W[k * st + j] *= rd;
  }
  __syncthreads();
}

// ---- trtri for the 64x64 Q factor (uses Vd as 4 full 16x16 blocks) ----
__device__ void trtri_small(float* W, int n, int st, float* Vd, int tid) {
  const int nblk = n >> 4;
  if (tid < nblk * 16) {
    const int blk = tid >> 4, c = tid & 15;
    const float* D = W + (16 * blk) * st + 16 * blk;
    float vv[16];
#pragma unroll
    for (int i = 15; i >= 0; --i) {
      float acc = 0.0f;
      for (int k = i + 1; k < 16; ++k) acc += D[i * st + k] * vv[k];
      const float di = D[i * st + i];
      const float val = (i == c) ? (1.0f / di) : (-acc / di);
      vv[i] = (i <= c) ? val : 0.0f;
    }
#pragma unroll
    for (int i = 0; i < 16; ++i) Vd[blk * 256 + i * 16 + c] = vv[i];
  }
  __syncthreads();
  for (int J = 0; J < nblk; ++J) {
    const int Jb = 16 * J;
    if (tid < Jb) {
      const int k = tid;
      float u[16], o[16];
#pragma unroll
      for (int jj = 0; jj < 16; ++jj) u[jj] = W[k * st + Jb + jj];
#pragma unroll
      for (int c = 0; c < 16; ++c) {
        float acc = 0.0f;
#pragma unroll
        for (int jj = 0; jj <= c; ++jj) acc += u[jj] * Vd[J * 256 + jj * 16 + c];
        o[c] = acc;
      }
#pragma unroll
      for (int c = 0; c < 16; ++c) W[k * st + Jb + c] = o[c];
    }
    __syncthreads();
    const int nOff = Jb * 16;
    const int nTot = nOff + 256;
    float rbuf[2];
    int cnt = 0;
    for (int id = tid; id < nTot; id += NT) {
      float val;
      if (id < nOff) {
        const int i = id >> 4, c = id & 15;
        float acc = 0.0f;
        for (int k = i; k < Jb; ++k) acc += W[i * st + k] * W[k * st + Jb + c];
        val = -acc;
      } else {
        val = Vd[J * 256 + (id - nOff)];
      }
      rbuf[cnt++] = val;
    }
    __syncthreads();
    cnt = 0;
    for (int id = tid; id < nTot; id += NT) {
      int i, c;
      if (id < nOff) { i = id >> 4; c = id & 15; }
      else { const int l = id - nOff; i = Jb + (l >> 4); c = l & 15; }
      W[i * st + Jb + c] = rbuf[cnt++];
    }
    __syncthreads();
  }
}

// ---- trtri for the 128 factor at stride WST; NEVER writes below the diag ----
__device__ void trtri128(Smem& sm, int tid) {
  if (tid < 128) {  // invert 16x16 diag blocks -> packed Vd (136/block)
    const int blk = tid >> 4, c = tid & 15;
    const float* D = sm.W + (blk << 4) * WST + (blk << 4);
    float vv[16];
#pragma unroll
    for (int i = 15; i >= 0; --i) {
      float acc = 0.0f;
      for (int k = i + 1; k < 16; ++k) acc += D[i * WST + k] * vv[k];
      const float di = D[i * WST + i];
      const float val = (i == c) ? (1.0f / di) : (-acc / di);
      vv[i] = (i <= c) ? val : 0.0f;
    }
#pragma unroll
    for (int i = 0; i < 16; ++i)
      if (i <= c) sm.Vd[blk * 136 + pk16(i) + (c - i)] = vv[i];
  }
  __syncthreads();
  for (int J = 0; J < 8; ++J) {
    const int Jb = J << 4;
    if (J > 0) {
      if (tid < Jb) {  // stage A: U' = U[0:Jb, Jblk] * Vd[J] (rows < Jb: upper only)
        float u[16], o[16];
        float2* wr = (float2*)&sm.W[tid * WST + Jb];
#pragma unroll
        for (int q = 0; q < 8; ++q) { const float2 v = wr[q]; u[2*q] = v.x; u[2*q+1] = v.y; }
        const float* vd = sm.Vd + J * 136;
#pragma unroll
        for (int c = 0; c < 16; ++c) {
          float acc = 0.0f;
#pragma unroll
          for (int jj = 0; jj <= c; ++jj) acc += u[jj] * vd[pk16(jj) + (c - jj)];
          o[c] = acc;
        }
#pragma unroll
        for (int q = 0; q < 8; ++q) wr[q] = make_float2(o[2*q], o[2*q+1]);
      }
      __syncthreads();
    }
    // stage B: M = -V[:,0:Jb] * U'  (rows < Jb: always upper) + guarded diag copy
    const int nStrip = Jb << 2;
    float acc[4] = {0.0f, 0.0f, 0.0f, 0.0f};
    int wi = 0, wc = 0;
    if (tid < nStrip) {
      wi = tid >> 2; wc = (tid & 3) << 2;
      for (int k = wi; k < Jb; ++k) {
        const float v = sm.W[wi * WST + k];
        const float2 u0 = *(const float2*)&sm.W[k * WST + Jb + wc];
        const float2 u1 = *(const float2*)&sm.W[k * WST + Jb + wc + 2];
        acc[0] = fmaf(v, u0.x, acc[0]); acc[1] = fmaf(v, u0.y, acc[1]);
        acc[2] = fmaf(v, u1.x, acc[2]); acc[3] = fmaf(v, u1.y, acc[3]);
      }
      acc[0] = -acc[0]; acc[1] = -acc[1]; acc[2] = -acc[2]; acc[3] = -acc[3];
    } else if (tid < nStrip + 64) {
      const int l = tid - nStrip;
      const int r = l >> 2; wi = Jb + r; wc = (l & 3) << 2;
      const float* vp = sm.Vd + J * 136 + pk16(r) - r;
#pragma unroll
      for (int q = 0; q < 4; ++q) {
        const int c = wc + q;
        acc[q] = (c >= r) ? vp[c] : 0.0f;
      }
    }
    __syncthreads();
    if (tid < nStrip) {  // rows < Jb, cols >= Jb: strictly upper -> fast writes
      *(float2*)&sm.W[wi * WST + Jb + wc]     = make_float2(acc[0], acc[1]);
      *(float2*)&sm.W[wi * WST + Jb + wc + 2] = make_float2(acc[2], acc[3]);
    } else if (tid < nStrip + 64) {  // diag block: guard j >= i (protect R-lower)
      const int r = wi - Jb;
#pragma unroll
      for (int q = 0; q < 4; ++q)
        if (wc + q >= r) sm.W[wi * WST + Jb + wc + q] = acc[q];
    }
    __syncthreads();
  }
}

// ---- owner-group elimination of 4 pivot rows + panel publish (phase q) ----
__device__ __forceinline__ void elim_publish(Smem& sm, float (&Wt)[4][8],
                                             float (&sq)[4], int q, int tc) {
  const int tcd = q >> 1;          // thread column holding the 4x4 diag block
  const int co = (q & 1) << 2;     // its column offset within the 8-col tile
  float L10 = 0, L20 = 0, L30 = 0, L21 = 0, L31 = 0, L32 = 0;
  float id0 = 0, id1 = 0, id2 = 0, id3 = 0;
  if (tc == tcd) {  // local LDL elimination of the 4x4 diag block
    float D[4][4];
#pragma unroll
    for (int m = 0; m < 4; ++m)
#pragma unroll
      for (int c = 0; c < 4; ++c) D[m][c] = Wt[m][co + c];
    id0 = 1.0f / D[0][0];
    L10 = D[0][1] * id0; L20 = D[0][2] * id0; L30 = D[0][3] * id0;
#pragma unroll
    for (int c = 0; c < 4; ++c) {
      D[1][c] -= L10 * D[0][c]; D[2][c] -= L20 * D[0][c]; D[3][c] -= L30 * D[0][c];
    }
    id1 = 1.0f / D[1][1];
    L21 = D[1][2] * id1; L31 = D[1][3] * id1;
#pragma unroll
    for (int c = 0; c < 4; ++c) { D[2][c] -= L21 * D[1][c]; D[3][c] -= L31 * D[1][c]; }
    id2 = 1.0f / D[2][2];
    L32 = D[2][3] * id2;
#pragma unroll
    for (int c = 0; c < 4; ++c) D[3][c] -= L32 * D[2][c];
    id3 = 1.0f / D[3][3];
  }
  const int src = ((q & 3) << 4) + tcd;  // wave-local lane of tcd in the owner group
  L10 = __shfl(L10, src); L20 = __shfl(L20, src); L30 = __shfl(L30, src);
  L21 = __shfl(L21, src); L31 = __shfl(L31, src); L32 = __shfl(L32, src);
  id0 = __shfl(id0, src); id1 = __shfl(id1, src);
  id2 = __shfl(id2, src); id3 = __shfl(id3, src);
#pragma unroll
  for (int c = 0; c < 8; ++c) {  // apply (sequenced) elimination to own 8 cols
    Wt[1][c] = fmaf(-L10, Wt[0][c], Wt[1][c]);
    Wt[2][c] = fmaf(-L20, Wt[0][c], Wt[2][c]);
    Wt[2][c] = fmaf(-L21, Wt[1][c], Wt[2][c]);
    Wt[3][c] = fmaf(-L30, Wt[0][c], Wt[3][c]);
    Wt[3][c] = fmaf(-L31, Wt[1][c], Wt[3][c]);
    Wt[3][c] = fmaf(-L32, Wt[2][c], Wt[3][c]);
  }
  sq[0] = sqrtf(id0); sq[1] = sqrtf(id1); sq[2] = sqrtf(id2); sq[3] = sqrtf(id3);
  const int nb = q & 1;
  float* pp = sm.pr + nb * 512;
  const int j0 = tc << 3;
#pragma unroll
  for (int m = 0; m < 4; ++m) {
    *(float4*)&pp[m * 128 + j0]     = make_float4(Wt[m][0], Wt[m][1], Wt[m][2], Wt[m][3]);
    *(float4*)&pp[m * 128 + j0 + 4] = make_float4(Wt[m][4], Wt[m][5], Wt[m][6], Wt[m][7]);
  }
  if (tc == tcd) {
    sm.scalbuf[nb * 4 + 0] = id0; sm.scalbuf[nb * 4 + 1] = id1;
    sm.scalbuf[nb * 4 + 2] = id2; sm.scalbuf[nb * 4 + 3] = id3;
  }
}

// ---- rank-4 blocked register Cholesky of S = R + diag + eps, then V = U^{-1}.
// R is read from W's strictly-lower triangle + Rdiag; U is written to the
// upper triangle only (guarded at tile boundaries), preserving R.
__device__ void factor_S(Smem& sm, int init, int tid) {
  const int tr = tid >> 4, tc = tid & 15;
  const int i0 = tr << 2, j0 = tc << 3;
  float Wt[4][8];
  float sq[4] = {0, 0, 0, 0};
#pragma unroll
  for (int m = 0; m < 4; ++m) {
    const int i = i0 + m;
#pragma unroll
    for (int c = 0; c < 8; ++c) {
      const int j = j0 + c;
      float v;
      if (i < j)      v = sm.W[j * WST + i];
      else if (i > j) v = sm.W[i * WST + j];
      else            v = sm.Rdiag[i] + (init ? 1.0f : sm.s[i] / sm.z[i]) + 1e-6f;
      Wt[m][c] = v;
    }
  }
  if (tr == 0) elim_publish(sm, Wt, sq, 0, tc);
  __syncthreads();
  for (int p = 0; p <= 30; ++p) {
    const int pb = p & 1;
    if (tr > p) {
      const float* pp = sm.pr + pb * 512;
      const float id_0 = sm.scalbuf[pb * 4 + 0], id_1 = sm.scalbuf[pb * 4 + 1];
      const float id_2 = sm.scalbuf[pb * 4 + 2], id_3 = sm.scalbuf[pb * 4 + 3];
      const float idv[4] = {id_0, id_1, id_2, id_3};
#pragma unroll
      for (int mm = 0; mm < 4; ++mm) {  // branchless rank-4 update; garbage stays
        const float4 pv  = *(const float4*)&pp[mm * 128 + i0];   // in j<i cells only
        const float4 pj0 = *(const float4*)&pp[mm * 128 + j0];
        const float4 pj1 = *(const float4*)&pp[mm * 128 + j0 + 4];
        const float um0 = pv.x * idv[mm], um1 = pv.y * idv[mm];
        const float um2 = pv.z * idv[mm], um3 = pv.w * idv[mm];
        const float pjv[8] = {pj0.x, pj0.y, pj0.z, pj0.w, pj1.x, pj1.y, pj1.z, pj1.w};
#pragma unroll
        for (int c = 0; c < 8; ++c) {
          Wt[0][c] = fmaf(-um0, pjv[c], Wt[0][c]);
          Wt[1][c] = fmaf(-um1, pjv[c], Wt[1][c]);
          Wt[2][c] = fmaf(-um2, pjv[c], Wt[2][c]);
          Wt[3][c] = fmaf(-um3, pjv[c], Wt[3][c]);
        }
      }
      if (tr == p + 1) elim_publish(sm, Wt, sq, p + 1, tc);
    }
    __syncthreads();
  }
  // write U (sqrt-scaled) to the UPPER triangle of W only
  if (j0 + 7 >= i0) {
    if (j0 >= i0 + 3) {  // whole tile is j >= i: fast vector writes
#pragma unroll
      for (int m = 0; m < 4; ++m)
#pragma unroll
        for (int qq = 0; qq < 4; ++qq)
          *(float2*)&sm.W[(i0 + m) * WST + j0 + 2 * qq] =
              make_float2(Wt[m][2 * qq] * sq[m], Wt[m][2 * qq + 1] * sq[m]);
    } else {  // diagonal crosses the tile: guarded scalar writes
#pragma unroll
      for (int m = 0; m < 4; ++m) {
        const int i = i0 + m;
#pragma unroll
        for (int c = 0; c < 8; ++c) {
          const int j = j0 + c;
          if (j >= i) sm.W[i * WST + j] = Wt[m][c] * sq[m];
        }
      }
    }
  }
  __syncthreads();
  trtri128(sm, tid);
}

// ---- KKT solve: matvecs only. qreg = this thread's 8 Q^{-1} values. ----
__device__ void solve_kkt(Smem& sm, const float* qreg, const float* Gb, const float* Ab,
                          int has_rx, const float* rx, const float* rs,
                          int has_rz, const float* rz, float ry,
                          float* dx_t, float* ds_t, float* dz_t, int dy_slot,
                          int accum, int tid) {
  const float u11i = sm.scal[SC_U11I];
  const int o8 = tid >> 3, seg = tid & 7;
  if (has_rx) {  // t = Qinv rx via register Qi + 8-lane shfl reduce
    float acc = 0.0f;
#pragma unroll
    for (int c = 0; c < 8; ++c) acc += qreg[c] * rx[seg * 8 + c];
    acc += __shfl_down(acc, 4); acc += __shfl_down(acc, 2); acc += __shfl_down(acc, 1);
    if (seg == 0) sm.t[o8] = acc;
    __syncthreads();
  }
  {  // H = G t + rs/d - rz  (coalesced float4 row dots, 4-lane groups)
    const int i = tid >> 2, q = tid & 3;
    float acc = 0.0f;
    if (has_rx) {
      const float* gr = Gb + (i << 6) + (q << 4);
#pragma unroll
      for (int kk = 0; kk < 16; kk += 4) {
        const float4 g4 = *(const float4*)(gr + kk);
        const float4 t4 = *(const float4*)&sm.t[(q << 4) + kk];
        acc += g4.x * t4.x + g4.y * t4.y + g4.z * t4.z + g4.w * t4.w;
      }
    }
    acc += __shfl_down(acc, 2); acc += __shfl_down(acc, 1);
    if (q == 0) {
      if (rs) acc += rs[i] / sm.dd[i];
      if (has_rz) acc -= rz[i];
      sm.H[i] = acc;
    }
  }
  __syncthreads();
  if (tid < 64) {  // H1 = a.t - ry
    float v = has_rx ? (Ab[tid] * sm.t[tid]) : 0.0f;
    v = wred_sum(v);
    if (tid == 0) sm.scal[SC_H1] = v - ry;
  }
  __syncthreads();
  const float y1 = sm.scal[SC_H1] * u11i;
  {  // Y = V^T (H - u12 y1), 4-way split-k, fused adjust
    const int o = tid & 127, p = tid >> 7;
    const int k0 = p << 5;
    int k1 = k0 + 32; if (k1 > o + 1) k1 = o + 1;
    float acc = 0.0f;
    for (int k = k0; k < k1; ++k)
      acc += sm.W[k * WST + o] * (sm.H[k] - sm.u12[k] * y1);
    sm.Vd[(p << 7) + o] = acc;
  }
  __syncthreads();
  if (tid < 128) sm.Y[tid] = sm.Vd[tid] + sm.Vd[128 + tid] + sm.Vd[256 + tid] + sm.Vd[384 + tid];
  __syncthreads();
  {  // wz = -(V Y), 4-way split-k (stride-130 column reads: 2-way = free)
    const int o = tid & 127, p = tid >> 7;
    int k0 = p << 5; if (k0 < o) k0 = o;
    const int k1 = (p << 5) + 32;
    float acc = 0.0f;
    for (int k = k0; k < k1; ++k) acc += sm.W[o * WST + k] * sm.Y[k];
    sm.Vd[(p << 7) + o] = acc;
  }
  __syncthreads();
  if (tid < 128)  // wz lands in H (H is dead after Y)
    sm.H[tid] = -(sm.Vd[tid] + sm.Vd[128 + tid] + sm.Vd[256 + tid] + sm.Vd[384 + tid]);
  __syncthreads();
  if (tid < 64) {  // w_y
    float v = sm.u12[tid] * sm.H[tid] + sm.u12[tid + 64] * sm.H[tid + 64];
    v = wred_sum(v);
    if (tid == 0) {
      const float wy = -(y1 + v) * u11i;
      if (accum) sm.scal[dy_slot] += wy; else sm.scal[dy_slot] = wy;
      sm.scal[SC_WY] = wy;
    }
  }
  __syncthreads();
  const float wy = sm.scal[SC_WY];
  if (tid < 256) {  // g1 partials: -G^T wz (coalesced column reads)
    const int o = tid & 63, p = tid >> 6;
    float acc = 0.0f;
    for (int i = (p << 5); i < (p << 5) + 32; ++i) acc -= Gb[(i << 6) + o] * sm.H[i];
    sm.Vd[(p << 6) + o] = acc;
  } else if (tid < 384) {  // ds = (-rs - wz)/d ; dz = wz  (accumulate for corrector)
    const int i = tid - 256;
    const float wzv = sm.H[i];
    const float r = rs ? rs[i] : 0.0f;
    const float dsv = (-r - wzv) / sm.dd[i];
    if (accum) { ds_t[i] += dsv; dz_t[i] += wzv; }
    else       { ds_t[i] = dsv;  dz_t[i] = wzv; }
  }
  __syncthreads();
  if (tid < 64) {
    float acc = sm.Vd[tid] + sm.Vd[64 + tid] + sm.Vd[128 + tid] + sm.Vd[192 + tid]
              - Ab[tid] * wy;
    if (has_rx) acc -= rx[tid];
    sm.g1[tid] = acc;
  }
  __syncthreads();
  {  // dx = Qinv g1 via register Qi
    float acc = 0.0f;
#pragma unroll
    for (int c = 0; c < 8; ++c) acc += qreg[c] * sm.g1[seg * 8 + c];
    acc += __shfl_down(acc, 4); acc += __shfl_down(acc, 2); acc += __shfl_down(acc, 1);
    if (seg == 0) { if (accum) dx_t[o8] += acc; else dx_t[o8] = acc; }
  }
  __syncthreads();
}

__global__ __launch_bounds__(NT, 2)
void optnet_kernel(const float* __restrict__ Qg, const float* __restrict__ pg,
                   const float* __restrict__ Ag, const float* __restrict__ bg,
                   const float* __restrict__ Gg, const float* __restrict__ hg,
                   float* __restrict__ outg) {
  __shared__ Smem sm;
  const int bId = blockIdx.x;
  const int tid = threadIdx.x;
  const float* Qb = Qg + (size_t)bId * 4096;
  const float* pb = pg + (size_t)bId * 64;
  const float* Ab = Ag + (size_t)bId * 64;
  const float  bb = bg[bId];
  const float* Gb = Gg + (size_t)bId * 8192;
  const float* hb = hg + (size_t)bId * 128;

  // ---- pre-factor Q: chol + trtri at stride 68 -> V_Q (upper), zero lower
  for (int idx = tid; idx < 4096; idx += NT)
    sm.W[(idx >> 6) * 68 + (idx & 63)] = Qb[idx];
  if (tid < 128) sm.dd[tid] = 1.0f;
  __syncthreads();
  chol_ldl(sm.W, 64, 68, sm.scal, tid);
  trtri_small(sm.W, 64, 68, sm.Vd, tid);
  for (int idx = tid; idx < 4096; idx += NT) {
    const int i = idx >> 6, j = idx & 63;
    if (i > j) sm.W[i * 68 + j] = 0.0f;
  }
  __syncthreads();
  // ---- Qinv into registers: thread (o8=tid>>3) holds Qi[o8][8*seg .. +8)
  float qreg[8];
  {
    const int o = tid >> 3, sgq = tid & 7;
#pragma unroll
    for (int c = 0; c < 8; ++c) {
      const int j = sgq * 8 + c;
      float acc = 0.0f;
      for (int k = 0; k < 64; ++k) acc += sm.W[o * 68 + k] * sm.W[j * 68 + k];
      qreg[c] = acc;
    }
  }
  // ---- w = V_Q^T a (into t); u11
  if (tid < 64) {
    float acc = 0.0f;
    for (int m = 0; m < 64; ++m) acc += sm.W[m * 68 + tid] * Ab[m];
    sm.t[tid] = acc;
  }
  __syncthreads();
  if (tid < 64) {
    float v = sm.t[tid] * sm.t[tid];
    v = wred_sum(v);
    if (tid == 0) sm.scal[SC_U11I] = 1.0f / sqrtf(v);
  }
  __syncthreads();
  // ---- t1 = V_Q^T G^T (64 x 128) via staged G^T chunks; register 4x4 tiles
  {
    const int kt = tid & 15, jt = tid >> 4;
    const int k0 = kt << 2, j0 = jt << 2;
    float t1a[4][4] = {};
    for (int mc = 0; mc < 64; mc += 16) {
      for (int idx = tid; idx < 2048; idx += NT) {
        const int j = idx >> 4, mm = idx & 15;
        sm.W[GCO + mm * GCS + j] = Gb[j * 64 + mc + mm];
      }
      __syncthreads();
#pragma unroll 4
      for (int mm = 0; mm < 16; ++mm) {
        const float4 v = *(const float4*)&sm.W[(mc + mm) * 68 + k0];
        const float4 g = *(const float4*)&sm.W[GCO + mm * GCS + j0];
        const float vv[4] = {v.x, v.y, v.z, v.w};
        const float gg[4] = {g.x, g.y, g.z, g.w};
#pragma unroll
        for (int a = 0; a < 4; ++a)
#pragma unroll
          for (int b2 = 0; b2 < 4; ++b2) t1a[a][b2] = fmaf(vv[a], gg[b2], t1a[a][b2]);
      }
      __syncthreads();
    }
#pragma unroll
    for (int a = 0; a < 4; ++a)
      *(float4*)&sm.W[T1O + (k0 + a) * T1S + j0] =
          make_float4(t1a[a][0], t1a[a][1], t1a[a][2], t1a[a][3]);
  }
  __syncthreads();
  // ---- u12 = (t1^T w) * u11i  (split-k over 4 groups)
  {
    const int o = tid & 127, p = tid >> 7;
    float acc = 0.0f;
    for (int k = (p << 4); k < (p << 4) + 16; ++k)
      acc += sm.W[T1O + k * T1S + o] * sm.t[k];
    sm.Vd[(p << 7) + o] = acc;
  }
  __syncthreads();
  if (tid < 128)
    sm.u12[tid] = (sm.Vd[tid] + sm.Vd[128 + tid] + sm.Vd[256 + tid] + sm.Vd[384 + tid])
                  * sm.scal[SC_U11I];
  __syncthreads();
  // ---- R = t1^T t1 - u12 u12^T: compute tile in (transient) registers ...
  float racc[4][8];
  {
    const int tr = tid >> 4, tc = tid & 15;
    const int i0 = tr << 2, j0 = tc << 3;
#pragma unroll
    for (int m = 0; m < 4; ++m)
#pragma unroll
      for (int c = 0; c < 8; ++c) racc[m][c] = 0.0f;
    for (int k = 0; k < 64; ++k) {
      const float4 a  = *(const float4*)&sm.W[T1O + k * T1S + i0];
      const float4 b0 = *(const float4*)&sm.W[T1O + k * T1S + j0];
      const float4 b1 = *(const float4*)&sm.W[T1O + k * T1S + j0 + 4];
      const float av[4] = {a.x, a.y, a.z, a.w};
      const float bv[8] = {b0.x, b0.y, b0.z, b0.w, b1.x, b1.y, b1.z, b1.w};
#pragma unroll
      for (int m = 0; m < 4; ++m)
#pragma unroll
        for (int c = 0; c < 8; ++c) racc[m][c] = fmaf(av[m], bv[c], racc[m][c]);
    }
#pragma unroll
    for (int m = 0; m < 4; ++m) {
      const float ui = sm.u12[i0 + m];
#pragma unroll
      for (int c = 0; c < 8; ++c) racc[m][c] -= ui * sm.u12[j0 + c];
    }
  }
  // ---- ... then park R in W's strictly-lower triangle (i<j at W[j][i]) +
  // Rdiag. Must barrier first: racc reads t1 (aliases the W cells we write).
  __syncthreads();
  {
    const int tr = tid >> 4, tc = tid & 15;
    const int i0 = tr << 2, j0 = tc << 3;
#pragma unroll
    for (int m = 0; m < 4; ++m) {
      const int i = i0 + m;
#pragma unroll
      for (int c = 0; c < 8; ++c) {
        const int j = j0 + c;
        if (i < j)       sm.W[j * WST + i] = racc[m][c];
        else if (i == j) sm.Rdiag[i] = racc[m][c];
      }
    }
  }
  if (tid < 128) sm.rz[tid] = -hb[tid];
  __syncthreads();

  // ---- initial factor + solve (d = 1)
  factor_S(sm, 1, tid);
  solve_kkt(sm, qreg, Gb, Ab, 1, pb, nullptr, 1, sm.rz, -bb,
            sm.x, sm.s, sm.z, SC_Y, 0, tid);
  if (tid < 64) {
    float v = fminf(sm.s[tid], sm.s[tid + 64]);
    v = wred_min(v);
    if (tid == 0) sm.scal[SC_MINS] = v;
  } else if (tid < 128) {
    const int l = tid - 64;
    float v = fminf(sm.z[l], sm.z[l + 64]);
    v = wred_min(v);
    if (l == 0) sm.scal[SC_MINZ] = v;
  }
  __syncthreads();
  if (tid < 128) {
    const float cs = 1.0f - sm.scal[SC_MINS];
    if (cs > 1.0f) sm.s[tid] += cs;
  } else if (tid < 256) {
    const int i = tid - 128;
    const float cz = 1.0f - sm.scal[SC_MINZ];
    if (cz > 1.0f) sm.z[i] += cz;
  }
  __syncthreads();

  // ---- 5 IPM iterations
  for (int it = 0; it < 5; ++it) {
    if (tid < 256) {  // rx partials: G^T z + Q x (coalesced column reads)
      const int o = tid & 63, pq = tid >> 6;
      float acc = 0.0f;
      for (int i = (pq << 5); i < (pq << 5) + 32; ++i) acc += Gb[(i << 6) + o] * sm.z[i];
      for (int k = (pq << 4); k < (pq << 4) + 16; ++k) acc += Qb[(k << 6) + o] * sm.x[k];
      sm.Vd[(pq << 6) + o] = acc;
    } else {  // rz = G x + s - h (coalesced row dots, 2-lane groups)
      const int l = tid - 256, i = l >> 1, q = l & 1;
      const float* gr = Gb + (i << 6) + (q << 5);
      float acc = 0.0f;
#pragma unroll
      for (int kk = 0; kk < 32; kk += 4) {
        const float4 g4 = *(const float4*)(gr + kk);
        const float4 x4 = *(const float4*)&sm.x[(q << 5) + kk];
        acc += g4.x * x4.x + g4.y * x4.y + g4.z * x4.z + g4.w * x4.w;
      }
      acc += __shfl_down(acc, 1);
      if (q == 0) sm.rz[i] = acc + sm.s[i] - hb[i];
    }
    __syncthreads();
    if (tid < 64)
      sm.rxv[tid] = pb[tid] + Ab[tid] * sm.scal[SC_Y]
                  + sm.Vd[tid] + sm.Vd[64 + tid] + sm.Vd[128 + tid] + sm.Vd[192 + tid];
    __syncthreads();
    if (tid < 64) {  // ry
      float v = Ab[tid] * sm.x[tid];
      v = wred_sum(v);
      if (tid == 0) sm.scal[SC_RY] = v - bb;
    } else if (tid < 128) {  // mu
      const int l = tid - 64;
      float v = sm.s[l] * sm.z[l] + sm.s[l + 64] * sm.z[l + 64];
      v = wred_sum(v);
      if (l == 0) sm.scal[SC_MU] = v * (1.0f / 128.0f);
    } else if (tid < 256) {
      const int i = tid - 128;
      sm.dd[i] = sm.z[i] / sm.s[i];
    }
    __syncthreads();
    factor_S(sm, 0, tid);
    // affine predictor (rs = z)
    solve_kkt(sm, qreg, Gb, Ab, 1, sm.rxv, sm.z, 1, sm.rz, sm.scal[SC_RY],
              sm.dxa, sm.dsa, sm.dza, SC_DYA, 0, tid);
    if (tid < 64) {  // alpha_aff
      float m = __builtin_inff();
#pragma unroll
      for (int rep = 0; rep < 2; ++rep) {
        const int i = tid + 64 * rep;
        m = fminf(m, step_val(sm.z[i], sm.dza[i]));
        m = fminf(m, step_val(sm.s[i], sm.dsa[i]));
      }
      m = wred_min(m);
      if (tid == 0) sm.scal[SC_ALPHA] = 0.999f * fminf(m, 1.0f);
    }
    __syncthreads();
    {
      const float alpha = sm.scal[SC_ALPHA];
      if (tid < 64) {  // sigma -> mu_sig
        float v = 0.0f;
#pragma unroll
        for (int rep = 0; rep < 2; ++rep) {
          const int i = tid + 64 * rep;
          v += (sm.s[i] + alpha * sm.dsa[i]) * (sm.z[i] + alpha * sm.dza[i]);
        }
        v = wred_sum(v);
        if (tid == 0) {
          const float mu = sm.scal[SC_MU];
          const float r = v / (mu * 128.0f);
          sm.scal[SC_MUSIG] = -mu * r * r * r;
        }
      }
    }
    __syncthreads();
    if (tid < 128)  // non_zero (uses AFFINE dsa/dza; reuse rz buffer)
      sm.rz[tid] = (sm.scal[SC_MUSIG] + sm.dsa[tid] * sm.dza[tid]) / sm.s[tid];
    __syncthreads();
    // corrector: accumulates into dxa/dsa/dza/SC_DYA
    solve_kkt(sm, qreg, Gb, Ab, 0, nullptr, sm.rz, 0, nullptr, 0.0f,
              sm.dxa, sm.dsa, sm.dza, SC_DYA, 1, tid);
    if (tid < 64) {  // alpha on combined step
      float m = __builtin_inff();
#pragma unroll
      for (int rep = 0; rep < 2; ++rep) {
        const int i = tid + 64 * rep;
        m = fminf(m, step_val(sm.z[i], sm.dza[i]));
        m = fminf(m, step_val(sm.s[i], sm.dsa[i]));
      }
      m = wred_min(m);
      if (tid == 0) sm.scal[SC_ALPHA] = 0.999f * fminf(m, 1.0f);
    }
    __syncthreads();
    {
      const float a2 = sm.scal[SC_ALPHA];
      if (tid < 128) sm.s[tid] += a2 * sm.dsa[tid];
      else if (tid < 256) sm.z[tid - 128] += a2 * sm.dza[tid - 128];
    }
    if (tid < 64) sm.x[tid] += sm.scal[SC_ALPHA] * sm.dxa[tid];
    if (tid == 64) sm.scal[SC_Y] += sm.scal[SC_ALPHA] * sm.scal[SC_DYA];
    __syncthreads();
  }
  if (tid < 64) outg[((size_t)bId << 6) + tid] = sm.x[tid];
}

extern "C" void kernel_launch(void* const* d_in, const int* in_sizes, int n_in,
                              void* d_out, int out_size, void* d_ws, size_t ws_size,
                              hipStream_t stream) {
  (void)n_in; (void)d_ws; (void)ws_size; (void)out_size;
  const float* Q = (const float*)d_in[0];
  const float* p = (const float*)d_in[1];
  const float* A = (const float*)d_in[2];
  const float* b = (const float*)d_in[3];
  const float* G = (const float*)d_in[4];
  const float* h = (const float*)d_in[5];
  const int B = in_sizes[3];  // b has one element per batch
  optnet_kernel<<<B, NT, 0, stream>>>(Q, p, A, b, G, h, (float*)d_out);
}

// Round 8
// 3340.795 us; speedup vs baseline: 1.4520x; 1.1097x over previous
//
#include <hip/hip_runtime.h>
#include <math.h>

// OptNet batched QP IPM solver — Round 7 (resubmitted unchanged after an
// infrastructure failure: "MI355X container failed twice", no kernel signal;
// same transient failure mode as round 5, which cleared on resubmission).
// One 512-thread block per batch element; targets 2 blocks/CU (LDS 81504 B).
// R7: eliminate the residual scratch spill (R6: 2.4 GB/dispatch HBM scratch,
// ~1 float4 per chol-phase iteration). Peak VGPR pressure in factor_S's phase
// loop is cut under the 128 cap: unroll-1 on the phase/mm loops (3 float4
// loads in flight, not 12), sq[] live-through replaced by parking inverse
// diagonals in sm.Y (dead during factor_S), unroll-2 on the racc build loop.
// R parked in W's strictly-lower triangle + Rdiag (R5); rank-4 register chol
// (33 barriers); W stride 130 (2-way LDS conflicts = free).

#define NT  512
#define WST 130    // factor/V stride: 130 % 32 = 2 -> 2-way column conflicts (free)
#define T1O 4352   // t1 = V_Q^T G^T (64 x 128) offset inside W
#define T1S 132
#define GCO 12800  // G^T staging chunk offset inside W
#define GCS 132

struct __align__(16) Smem {
  float W[16640];     // 66560 B: upper = factor/V; strictly-lower = R (transposed)
  float Vd[1088];     // packed trtri diag inverses (8x136) / split-k scratch (<=512)
  float pr[1024];     // chol pivot panel, double-buffered 2 x (4 x 128)
  float x[64], rxv[64], g1[64], t[64], dxa[64];
  float s[128], z[128], rz[128], dsa[128], dza[128], u12[128], dd[128], H[128], Y[128];
  float Rdiag[128];   // R's diagonal (lower triangle of W can't hold it)
  float scalbuf[8];   // chol inv-diag, double-buffered 2 x 4
  float scal[16];
};
static_assert(sizeof(Smem) <= 81920, "LDS must fit 2 blocks/CU");

enum { SC_D0 = 0, SC_D1 = 1, SC_H1 = 2, SC_U11I = 4, SC_RY = 5, SC_MU = 6,
       SC_ALPHA = 7, SC_MUSIG = 8, SC_Y = 9, SC_DYA = 10, SC_WY = 11,
       SC_MINS = 12, SC_MINZ = 13 };

__device__ __forceinline__ float wred_sum(float v) {
#pragma unroll
  for (int off = 32; off > 0; off >>= 1) v += __shfl_down(v, off);
  return v;
}
__device__ __forceinline__ float wred_min(float v) {
#pragma unroll
  for (int off = 32; off > 0; off >>= 1) v = fminf(v, __shfl_down(v, off));
  return v;
}
__device__ __forceinline__ float step_val(float v, float dv) {
  float a = -v / dv;
  return (a > 0.0f) ? a : __builtin_inff();  // NaN -> inf (matches ref)
}
__device__ __forceinline__ constexpr int pk16(int i) {  // packed 16x16 upper row start
  return i * 16 - ((i * (i - 1)) >> 1);
}

// ---- LDS chol, 1 barrier/column (only for the cheap 64x64 Q pre-factor) ----
__device__ void chol_ldl(float* W, int n, int st, float* dinv2, int tid) {
  if (tid == 0) dinv2[SC_D0] = 1.0f / W[0];
  __syncthreads();
  for (int k = 0; k < n - 1; ++k) {
    const float invd = dinv2[k & 1];
    const int row = k + 1 + (tid >> 1);
    if (row < n) {
      const float m = W[k * st + row] * invd;
      for (int j = row + (tid & 1); j < n; j += 2)
        W[row * st + j] -= m * W[k * st + j];
      if (tid == 0) dinv2[(k + 1) & 1] = 1.0f / W[row * st + row];
    }
    __syncthreads();
  }
  for (int k = tid; k < n; k += NT) {
    const float rd = 1.0f / sqrtf(W[k * st + k]);
    for (int j = k; j < n; ++j) W[k * st + j] *= rd;
  }
  __syncthreads();
}

// ---- trtri for the 64x64 Q factor (uses Vd as 4 full 16x16 blocks) ----
__device__ void trtri_small(float* W, int n, int st, float* Vd, int tid) {
  const int nblk = n >> 4;
  if (tid < nblk * 16) {
    const int blk = tid >> 4, c = tid & 15;
    const float* D = W + (16 * blk) * st + 16 * blk;
    float vv[16];
#pragma unroll
    for (int i = 15; i >= 0; --i) {
      float acc = 0.0f;
      for (int k = i + 1; k < 16; ++k) acc += D[i * st + k] * vv[k];
      const float di = D[i * st + i];
      const float val = (i == c) ? (1.0f / di) : (-acc / di);
      vv[i] = (i <= c) ? val : 0.0f;
    }
#pragma unroll
    for (int i = 0; i < 16; ++i) Vd[blk * 256 + i * 16 + c] = vv[i];
  }
  __syncthreads();
  for (int J = 0; J < nblk; ++J) {
    const int Jb = 16 * J;
    if (tid < Jb) {
      const int k = tid;
      float u[16], o[16];
#pragma unroll
      for (int jj = 0; jj < 16; ++jj) u[jj] = W[k * st + Jb + jj];
#pragma unroll
      for (int c = 0; c < 16; ++c) {
        float acc = 0.0f;
#pragma unroll
        for (int jj = 0; jj <= c; ++jj) acc += u[jj] * Vd[J * 256 + jj * 16 + c];
        o[c] = acc;
      }
#pragma unroll
      for (int c = 0; c < 16; ++c) W[k * st + Jb + c] = o[c];
    }
    __syncthreads();
    const int nOff = Jb * 16;
    const int nTot = nOff + 256;
    float rbuf[2];
    int cnt = 0;
    for (int id = tid; id < nTot; id += NT) {
      float val;
      if (id < nOff) {
        const int i = id >> 4, c = id & 15;
        float acc = 0.0f;
        for (int k = i; k < Jb; ++k) acc += W[i * st + k] * W[k * st + Jb + c];
        val = -acc;
      } else {
        val = Vd[J * 256 + (id - nOff)];
      }
      rbuf[cnt++] = val;
    }
    __syncthreads();
    cnt = 0;
    for (int id = tid; id < nTot; id += NT) {
      int i, c;
      if (id < nOff) { i = id >> 4; c = id & 15; }
      else { const int l = id - nOff; i = Jb + (l >> 4); c = l & 15; }
      W[i * st + Jb + c] = rbuf[cnt++];
    }
    __syncthreads();
  }
}

// ---- trtri for the 128 factor at stride WST; NEVER writes below the diag ----
__device__ void trtri128(Smem& sm, int tid) {
  if (tid < 128) {  // invert 16x16 diag blocks -> packed Vd (136/block)
    const int blk = tid >> 4, c = tid & 15;
    const float* D = sm.W + (blk << 4) * WST + (blk << 4);
    float vv[16];
#pragma unroll
    for (int i = 15; i >= 0; --i) {
      float acc = 0.0f;
      for (int k = i + 1; k < 16; ++k) acc += D[i * WST + k] * vv[k];
      const float di = D[i * WST + i];
      const float val = (i == c) ? (1.0f / di) : (-acc / di);
      vv[i] = (i <= c) ? val : 0.0f;
    }
#pragma unroll
    for (int i = 0; i < 16; ++i)
      if (i <= c) sm.Vd[blk * 136 + pk16(i) + (c - i)] = vv[i];
  }
  __syncthreads();
  for (int J = 0; J < 8; ++J) {
    const int Jb = J << 4;
    if (J > 0) {
      if (tid < Jb) {  // stage A: U' = U[0:Jb, Jblk] * Vd[J] (rows < Jb: upper only)
        float u[16], o[16];
        float2* wr = (float2*)&sm.W[tid * WST + Jb];
#pragma unroll
        for (int q = 0; q < 8; ++q) { const float2 v = wr[q]; u[2*q] = v.x; u[2*q+1] = v.y; }
        const float* vd = sm.Vd + J * 136;
#pragma unroll
        for (int c = 0; c < 16; ++c) {
          float acc = 0.0f;
#pragma unroll
          for (int jj = 0; jj <= c; ++jj) acc += u[jj] * vd[pk16(jj) + (c - jj)];
          o[c] = acc;
        }
#pragma unroll
        for (int q = 0; q < 8; ++q) wr[q] = make_float2(o[2*q], o[2*q+1]);
      }
      __syncthreads();
    }
    // stage B: M = -V[:,0:Jb] * U'  (rows < Jb: always upper) + guarded diag copy
    const int nStrip = Jb << 2;
    float acc[4] = {0.0f, 0.0f, 0.0f, 0.0f};
    int wi = 0, wc = 0;
    if (tid < nStrip) {
      wi = tid >> 2; wc = (tid & 3) << 2;
      for (int k = wi; k < Jb; ++k) {
        const float v = sm.W[wi * WST + k];
        const float2 u0 = *(const float2*)&sm.W[k * WST + Jb + wc];
        const float2 u1 = *(const float2*)&sm.W[k * WST + Jb + wc + 2];
        acc[0] = fmaf(v, u0.x, acc[0]); acc[1] = fmaf(v, u0.y, acc[1]);
        acc[2] = fmaf(v, u1.x, acc[2]); acc[3] = fmaf(v, u1.y, acc[3]);
      }
      acc[0] = -acc[0]; acc[1] = -acc[1]; acc[2] = -acc[2]; acc[3] = -acc[3];
    } else if (tid < nStrip + 64) {
      const int l = tid - nStrip;
      const int r = l >> 2; wi = Jb + r; wc = (l & 3) << 2;
      const float* vp = sm.Vd + J * 136 + pk16(r) - r;
#pragma unroll
      for (int q = 0; q < 4; ++q) {
        const int c = wc + q;
        acc[q] = (c >= r) ? vp[c] : 0.0f;
      }
    }
    __syncthreads();
    if (tid < nStrip) {  // rows < Jb, cols >= Jb: strictly upper -> fast writes
      *(float2*)&sm.W[wi * WST + Jb + wc]     = make_float2(acc[0], acc[1]);
      *(float2*)&sm.W[wi * WST + Jb + wc + 2] = make_float2(acc[2], acc[3]);
    } else if (tid < nStrip + 64) {  // diag block: guard j >= i (protect R-lower)
      const int r = wi - Jb;
#pragma unroll
      for (int q = 0; q < 4; ++q)
        if (wc + q >= r) sm.W[wi * WST + Jb + wc + q] = acc[q];
    }
    __syncthreads();
  }
}

// ---- owner-group elimination of 4 pivot rows + panel publish (phase q).
// Inverse diagonals land in scalbuf (next-phase broadcast) AND sm.Y[4q..4q+3]
// (read back at the final U-write — removes the sq[4] live-through). ----
__device__ __forceinline__ void elim_publish(Smem& sm, float (&Wt)[4][8],
                                             int q, int tc) {
  const int tcd = q >> 1;          // thread column holding the 4x4 diag block
  const int co = (q & 1) << 2;     // its column offset within the 8-col tile
  float L10 = 0, L20 = 0, L30 = 0, L21 = 0, L31 = 0, L32 = 0;
  float id0 = 0, id1 = 0, id2 = 0, id3 = 0;
  if (tc == tcd) {  // local LDL elimination of the 4x4 diag block
    float D[4][4];
#pragma unroll
    for (int m = 0; m < 4; ++m)
#pragma unroll
      for (int c = 0; c < 4; ++c) D[m][c] = Wt[m][co + c];
    id0 = 1.0f / D[0][0];
    L10 = D[0][1] * id0; L20 = D[0][2] * id0; L30 = D[0][3] * id0;
#pragma unroll
    for (int c = 0; c < 4; ++c) {
      D[1][c] -= L10 * D[0][c]; D[2][c] -= L20 * D[0][c]; D[3][c] -= L30 * D[0][c];
    }
    id1 = 1.0f / D[1][1];
    L21 = D[1][2] * id1; L31 = D[1][3] * id1;
#pragma unroll
    for (int c = 0; c < 4; ++c) { D[2][c] -= L21 * D[1][c]; D[3][c] -= L31 * D[1][c]; }
    id2 = 1.0f / D[2][2];
    L32 = D[2][3] * id2;
#pragma unroll
    for (int c = 0; c < 4; ++c) D[3][c] -= L32 * D[2][c];
    id3 = 1.0f / D[3][3];
  }
  const int src = ((q & 3) << 4) + tcd;  // wave-local lane of tcd in the owner group
  L10 = __shfl(L10, src); L20 = __shfl(L20, src); L30 = __shfl(L30, src);
  L21 = __shfl(L21, src); L31 = __shfl(L31, src); L32 = __shfl(L32, src);
#pragma unroll
  for (int c = 0; c < 8; ++c) {  // apply (sequenced) elimination to own 8 cols
    Wt[1][c] = fmaf(-L10, Wt[0][c], Wt[1][c]);
    Wt[2][c] = fmaf(-L20, Wt[0][c], Wt[2][c]);
    Wt[2][c] = fmaf(-L21, Wt[1][c], Wt[2][c]);
    Wt[3][c] = fmaf(-L30, Wt[0][c], Wt[3][c]);
    Wt[3][c] = fmaf(-L31, Wt[1][c], Wt[3][c]);
    Wt[3][c] = fmaf(-L32, Wt[2][c], Wt[3][c]);
  }
  const int nb = q & 1;
  float* pp = sm.pr + nb * 512;
  const int j0 = tc << 3;
#pragma unroll
  for (int m = 0; m < 4; ++m) {
    *(float4*)&pp[m * 128 + j0]     = make_float4(Wt[m][0], Wt[m][1], Wt[m][2], Wt[m][3]);
    *(float4*)&pp[m * 128 + j0 + 4] = make_float4(Wt[m][4], Wt[m][5], Wt[m][6], Wt[m][7]);
  }
  if (tc == tcd) {
    sm.scalbuf[nb * 4 + 0] = id0; sm.scalbuf[nb * 4 + 1] = id1;
    sm.scalbuf[nb * 4 + 2] = id2; sm.scalbuf[nb * 4 + 3] = id3;
    sm.Y[(q << 2) + 0] = id0; sm.Y[(q << 2) + 1] = id1;
    sm.Y[(q << 2) + 2] = id2; sm.Y[(q << 2) + 3] = id3;
  }
}

// ---- rank-4 blocked register Cholesky of S = R + diag + eps, then V = U^{-1}.
// R is read from W's strictly-lower triangle + Rdiag; U is written to the
// upper triangle only (guarded at tile boundaries), preserving R.
__device__ void factor_S(Smem& sm, int init, int tid) {
  const int tr = tid >> 4, tc = tid & 15;
  const int i0 = tr << 2, j0 = tc << 3;
  float Wt[4][8];
#pragma unroll
  for (int m = 0; m < 4; ++m) {
    const int i = i0 + m;
#pragma unroll
    for (int c = 0; c < 8; ++c) {
      const int j = j0 + c;
      float v;
      if (i < j)      v = sm.W[j * WST + i];
      else if (i > j) v = sm.W[i * WST + j];
      else            v = sm.Rdiag[i] + (init ? 1.0f : sm.s[i] / sm.z[i]) + 1e-6f;
      Wt[m][c] = v;
    }
  }
  if (tr == 0) elim_publish(sm, Wt, 0, tc);
  __syncthreads();
#pragma unroll 1
  for (int p = 0; p <= 30; ++p) {
    const int pb = p & 1;
    if (tr > p) {
      const float* pp = sm.pr + pb * 512;
      const float idv0 = sm.scalbuf[pb * 4 + 0], idv1 = sm.scalbuf[pb * 4 + 1];
      const float idv2 = sm.scalbuf[pb * 4 + 2], idv3 = sm.scalbuf[pb * 4 + 3];
#pragma unroll 1
      for (int mm = 0; mm < 4; ++mm) {  // unroll-1: only 3 float4 loads in flight
        const float idm = (mm == 0) ? idv0 : (mm == 1) ? idv1 : (mm == 2) ? idv2 : idv3;
        const float4 pv  = *(const float4*)&pp[mm * 128 + i0];   // garbage stays
        const float4 pj0 = *(const float4*)&pp[mm * 128 + j0];   // in j<i cells
        const float4 pj1 = *(const float4*)&pp[mm * 128 + j0 + 4];
        const float um0 = pv.x * idm, um1 = pv.y * idm;
        const float um2 = pv.z * idm, um3 = pv.w * idm;
        const float pjv[8] = {pj0.x, pj0.y, pj0.z, pj0.w, pj1.x, pj1.y, pj1.z, pj1.w};
#pragma unroll
        for (int c = 0; c < 8; ++c) {
          Wt[0][c] = fmaf(-um0, pjv[c], Wt[0][c]);
          Wt[1][c] = fmaf(-um1, pjv[c], Wt[1][c]);
          Wt[2][c] = fmaf(-um2, pjv[c], Wt[2][c]);
          Wt[3][c] = fmaf(-um3, pjv[c], Wt[3][c]);
        }
      }
      if (tr == p + 1) elim_publish(sm, Wt, p + 1, tc);
    }
    __syncthreads();
  }
  // write U (sqrt-scaled) to the UPPER triangle of W only; inv-diags from Y
  if (j0 + 7 >= i0) {
    float sqv[4];
#pragma unroll
    for (int m = 0; m < 4; ++m) sqv[m] = sqrtf(sm.Y[i0 + m]);
    if (j0 >= i0 + 3) {  // whole tile is j >= i: fast vector writes
#pragma unroll
      for (int m = 0; m < 4; ++m)
#pragma unroll
        for (int qq = 0; qq < 4; ++qq)
          *(float2*)&sm.W[(i0 + m) * WST + j0 + 2 * qq] =
              make_float2(Wt[m][2 * qq] * sqv[m], Wt[m][2 * qq + 1] * sqv[m]);
    } else {  // diagonal crosses the tile: guarded scalar writes
#pragma unroll
      for (int m = 0; m < 4; ++m) {
        const int i = i0 + m;
#pragma unroll
        for (int c = 0; c < 8; ++c) {
          const int j = j0 + c;
          if (j >= i) sm.W[i * WST + j] = Wt[m][c] * sqv[m];
        }
      }
    }
  }
  __syncthreads();
  trtri128(sm, tid);
}

// ---- KKT solve: matvecs only. qreg = this thread's 8 Q^{-1} values. ----
__device__ void solve_kkt(Smem& sm, const float* qreg, const float* Gb, const float* Ab,
                          int has_rx, const float* rx, const float* rs,
                          int has_rz, const float* rz, float ry,
                          float* dx_t, float* ds_t, float* dz_t, int dy_slot,
                          int accum, int tid) {
  const float u11i = sm.scal[SC_U11I];
  const int o8 = tid >> 3, seg = tid & 7;
  if (has_rx) {  // t = Qinv rx via register Qi + 8-lane shfl reduce
    float acc = 0.0f;
#pragma unroll
    for (int c = 0; c < 8; ++c) acc += qreg[c] * rx[seg * 8 + c];
    acc += __shfl_down(acc, 4); acc += __shfl_down(acc, 2); acc += __shfl_down(acc, 1);
    if (seg == 0) sm.t[o8] = acc;
    __syncthreads();
  }
  {  // H = G t + rs/d - rz  (coalesced float4 row dots, 4-lane groups)
    const int i = tid >> 2, q = tid & 3;
    float acc = 0.0f;
    if (has_rx) {
      const float* gr = Gb + (i << 6) + (q << 4);
#pragma unroll
      for (int kk = 0; kk < 16; kk += 4) {
        const float4 g4 = *(const float4*)(gr + kk);
        const float4 t4 = *(const float4*)&sm.t[(q << 4) + kk];
        acc += g4.x * t4.x + g4.y * t4.y + g4.z * t4.z + g4.w * t4.w;
      }
    }
    acc += __shfl_down(acc, 2); acc += __shfl_down(acc, 1);
    if (q == 0) {
      if (rs) acc += rs[i] / sm.dd[i];
      if (has_rz) acc -= rz[i];
      sm.H[i] = acc;
    }
  }
  __syncthreads();
  if (tid < 64) {  // H1 = a.t - ry
    float v = has_rx ? (Ab[tid] * sm.t[tid]) : 0.0f;
    v = wred_sum(v);
    if (tid == 0) sm.scal[SC_H1] = v - ry;
  }
  __syncthreads();
  const float y1 = sm.scal[SC_H1] * u11i;
  {  // Y = V^T (H - u12 y1), 4-way split-k, fused adjust
    const int o = tid & 127, p = tid >> 7;
    const int k0 = p << 5;
    int k1 = k0 + 32; if (k1 > o + 1) k1 = o + 1;
    float acc = 0.0f;
    for (int k = k0; k < k1; ++k)
      acc += sm.W[k * WST + o] * (sm.H[k] - sm.u12[k] * y1);
    sm.Vd[(p << 7) + o] = acc;
  }
  __syncthreads();
  if (tid < 128) sm.Y[tid] = sm.Vd[tid] + sm.Vd[128 + tid] + sm.Vd[256 + tid] + sm.Vd[384 + tid];
  __syncthreads();
  {  // wz = -(V Y), 4-way split-k (stride-130 column reads: 2-way = free)
    const int o = tid & 127, p = tid >> 7;
    int k0 = p << 5; if (k0 < o) k0 = o;
    const int k1 = (p << 5) + 32;
    float acc = 0.0f;
    for (int k = k0; k < k1; ++k) acc += sm.W[o * WST + k] * sm.Y[k];
    sm.Vd[(p << 7) + o] = acc;
  }
  __syncthreads();
  if (tid < 128)  // wz lands in H (H is dead after Y)
    sm.H[tid] = -(sm.Vd[tid] + sm.Vd[128 + tid] + sm.Vd[256 + tid] + sm.Vd[384 + tid]);
  __syncthreads();
  if (tid < 64) {  // w_y
    float v = sm.u12[tid] * sm.H[tid] + sm.u12[tid + 64] * sm.H[tid + 64];
    v = wred_sum(v);
    if (tid == 0) {
      const float wy = -(y1 + v) * u11i;
      if (accum) sm.scal[dy_slot] += wy; else sm.scal[dy_slot] = wy;
      sm.scal[SC_WY] = wy;
    }
  }
  __syncthreads();
  const float wy = sm.scal[SC_WY];
  if (tid < 256) {  // g1 partials: -G^T wz (coalesced column reads)
    const int o = tid & 63, p = tid >> 6;
    float acc = 0.0f;
    for (int i = (p << 5); i < (p << 5) + 32; ++i) acc -= Gb[(i << 6) + o] * sm.H[i];
    sm.Vd[(p << 6) + o] = acc;
  } else if (tid < 384) {  // ds = (-rs - wz)/d ; dz = wz  (accumulate for corrector)
    const int i = tid - 256;
    const float wzv = sm.H[i];
    const float r = rs ? rs[i] : 0.0f;
    const float dsv = (-r - wzv) / sm.dd[i];
    if (accum) { ds_t[i] += dsv; dz_t[i] += wzv; }
    else       { ds_t[i] = dsv;  dz_t[i] = wzv; }
  }
  __syncthreads();
  if (tid < 64) {
    float acc = sm.Vd[tid] + sm.Vd[64 + tid] + sm.Vd[128 + tid] + sm.Vd[192 + tid]
              - Ab[tid] * wy;
    if (has_rx) acc -= rx[tid];
    sm.g1[tid] = acc;
  }
  __syncthreads();
  {  // dx = Qinv g1 via register Qi
    float acc = 0.0f;
#pragma unroll
    for (int c = 0; c < 8; ++c) acc += qreg[c] * sm.g1[seg * 8 + c];
    acc += __shfl_down(acc, 4); acc += __shfl_down(acc, 2); acc += __shfl_down(acc, 1);
    if (seg == 0) { if (accum) dx_t[o8] += acc; else dx_t[o8] = acc; }
  }
  __syncthreads();
}

__global__ __launch_bounds__(NT, 2)
void optnet_kernel(const float* __restrict__ Qg, const float* __restrict__ pg,
                   const float* __restrict__ Ag, const float* __restrict__ bg,
                   const float* __restrict__ Gg, const float* __restrict__ hg,
                   float* __restrict__ outg) {
  __shared__ Smem sm;
  const int bId = blockIdx.x;
  const int tid = threadIdx.x;
  const float* Qb = Qg + (size_t)bId * 4096;
  const float* pb = pg + (size_t)bId * 64;
  const float* Ab = Ag + (size_t)bId * 64;
  const float  bb = bg[bId];
  const float* Gb = Gg + (size_t)bId * 8192;
  const float* hb = hg + (size_t)bId * 128;

  // ---- pre-factor Q: chol + trtri at stride 68 -> V_Q (upper), zero lower
  for (int idx = tid; idx < 4096; idx += NT)
    sm.W[(idx >> 6) * 68 + (idx & 63)] = Qb[idx];
  if (tid < 128) sm.dd[tid] = 1.0f;
  __syncthreads();
  chol_ldl(sm.W, 64, 68, sm.scal, tid);
  trtri_small(sm.W, 64, 68, sm.Vd, tid);
  for (int idx = tid; idx < 4096; idx += NT) {
    const int i = idx >> 6, j = idx & 63;
    if (i > j) sm.W[i * 68 + j] = 0.0f;
  }
  __syncthreads();
  // ---- Qinv into registers: thread (o8=tid>>3) holds Qi[o8][8*seg .. +8)
  float qreg[8];
  {
    const int o = tid >> 3, sgq = tid & 7;
#pragma unroll 1
    for (int c = 0; c < 8; ++c) {
      const int j = sgq * 8 + c;
      float acc = 0.0f;
      for (int k = 0; k < 64; ++k) acc += sm.W[o * 68 + k] * sm.W[j * 68 + k];
      qreg[c] = acc;
    }
  }
  // ---- w = V_Q^T a (into t); u11
  if (tid < 64) {
    float acc = 0.0f;
    for (int m = 0; m < 64; ++m) acc += sm.W[m * 68 + tid] * Ab[m];
    sm.t[tid] = acc;
  }
  __syncthreads();
  if (tid < 64) {
    float v = sm.t[tid] * sm.t[tid];
    v = wred_sum(v);
    if (tid == 0) sm.scal[SC_U11I] = 1.0f / sqrtf(v);
  }
  __syncthreads();
  // ---- t1 = V_Q^T G^T (64 x 128) via staged G^T chunks; register 4x4 tiles
  {
    const int kt = tid & 15, jt = tid >> 4;
    const int k0 = kt << 2, j0 = jt << 2;
    float t1a[4][4] = {};
    for (int mc = 0; mc < 64; mc += 16) {
      for (int idx = tid; idx < 2048; idx += NT) {
        const int j = idx >> 4, mm = idx & 15;
        sm.W[GCO + mm * GCS + j] = Gb[j * 64 + mc + mm];
      }
      __syncthreads();
#pragma unroll 2
      for (int mm = 0; mm < 16; ++mm) {
        const float4 v = *(const float4*)&sm.W[(mc + mm) * 68 + k0];
        const float4 g = *(const float4*)&sm.W[GCO + mm * GCS + j0];
        const float vv[4] = {v.x, v.y, v.z, v.w};
        const float gg[4] = {g.x, g.y, g.z, g.w};
#pragma unroll
        for (int a = 0; a < 4; ++a)
#pragma unroll
          for (int b2 = 0; b2 < 4; ++b2) t1a[a][b2] = fmaf(vv[a], gg[b2], t1a[a][b2]);
      }
      __syncthreads();
    }
#pragma unroll
    for (int a = 0; a < 4; ++a)
      *(float4*)&sm.W[T1O + (k0 + a) * T1S + j0] =
          make_float4(t1a[a][0], t1a[a][1], t1a[a][2], t1a[a][3]);
  }
  __syncthreads();
  // ---- u12 = (t1^T w) * u11i  (split-k over 4 groups)
  {
    const int o = tid & 127, p = tid >> 7;
    float acc = 0.0f;
    for (int k = (p << 4); k < (p << 4) + 16; ++k)
      acc += sm.W[T1O + k * T1S + o] * sm.t[k];
    sm.Vd[(p << 7) + o] = acc;
  }
  __syncthreads();
  if (tid < 128)
    sm.u12[tid] = (sm.Vd[tid] + sm.Vd[128 + tid] + sm.Vd[256 + tid] + sm.Vd[384 + tid])
                  * sm.scal[SC_U11I];
  __syncthreads();
  // ---- R = t1^T t1 - u12 u12^T: compute tile in (transient) registers ...
  float racc[4][8];
  {
    const int tr = tid >> 4, tc = tid & 15;
    const int i0 = tr << 2, j0 = tc << 3;
#pragma unroll
    for (int m = 0; m < 4; ++m)
#pragma unroll
      for (int c = 0; c < 8; ++c) racc[m][c] = 0.0f;
#pragma unroll 2
    for (int k = 0; k < 64; ++k) {
      const float4 a  = *(const float4*)&sm.W[T1O + k * T1S + i0];
      const float4 b0 = *(const float4*)&sm.W[T1O + k * T1S + j0];
      const float4 b1 = *(const float4*)&sm.W[T1O + k * T1S + j0 + 4];
      const float av[4] = {a.x, a.y, a.z, a.w};
      const float bv[8] = {b0.x, b0.y, b0.z, b0.w, b1.x, b1.y, b1.z, b1.w};
#pragma unroll
      for (int m = 0; m < 4; ++m)
#pragma unroll
        for (int c = 0; c < 8; ++c) racc[m][c] = fmaf(av[m], bv[c], racc[m][c]);
    }
#pragma unroll
    for (int m = 0; m < 4; ++m) {
      const float ui = sm.u12[i0 + m];
#pragma unroll
      for (int c = 0; c < 8; ++c) racc[m][c] -= ui * sm.u12[j0 + c];
    }
  }
  // ---- ... then park R in W's strictly-lower triangle (i<j at W[j][i]) +
  // Rdiag. Must barrier first: racc reads t1 (aliases the W cells we write).
  __syncthreads();
  {
    const int tr = tid >> 4, tc = tid & 15;
    const int i0 = tr << 2, j0 = tc << 3;
#pragma unroll
    for (int m = 0; m < 4; ++m) {
      const int i = i0 + m;
#pragma unroll
      for (int c = 0; c < 8; ++c) {
        const int j = j0 + c;
        if (i < j)       sm.W[j * WST + i] = racc[m][c];
        else if (i == j) sm.Rdiag[i] = racc[m][c];
      }
    }
  }
  if (tid < 128) sm.rz[tid] = -hb[tid];
  __syncthreads();

  // ---- initial factor + solve (d = 1)
  factor_S(sm, 1, tid);
  solve_kkt(sm, qreg, Gb, Ab, 1, pb, nullptr, 1, sm.rz, -bb,
            sm.x, sm.s, sm.z, SC_Y, 0, tid);
  if (tid < 64) {
    float v = fminf(sm.s[tid], sm.s[tid + 64]);
    v = wred_min(v);
    if (tid == 0) sm.scal[SC_MINS] = v;
  } else if (tid < 128) {
    const int l = tid - 64;
    float v = fminf(sm.z[l], sm.z[l + 64]);
    v = wred_min(v);
    if (l == 0) sm.scal[SC_MINZ] = v;
  }
  __syncthreads();
  if (tid < 128) {
    const float cs = 1.0f - sm.scal[SC_MINS];
    if (cs > 1.0f) sm.s[tid] += cs;
  } else if (tid < 256) {
    const int i = tid - 128;
    const float cz = 1.0f - sm.scal[SC_MINZ];
    if (cz > 1.0f) sm.z[i] += cz;
  }
  __syncthreads();

  // ---- 5 IPM iterations
  for (int it = 0; it < 5; ++it) {
    if (tid < 256) {  // rx partials: G^T z + Q x (coalesced column reads)
      const int o = tid & 63, pq = tid >> 6;
      float acc = 0.0f;
      for (int i = (pq << 5); i < (pq << 5) + 32; ++i) acc += Gb[(i << 6) + o] * sm.z[i];
      for (int k = (pq << 4); k < (pq << 4) + 16; ++k) acc += Qb[(k << 6) + o] * sm.x[k];
      sm.Vd[(pq << 6) + o] = acc;
    } else {  // rz = G x + s - h (coalesced row dots, 2-lane groups)
      const int l = tid - 256, i = l >> 1, q = l & 1;
      const float* gr = Gb + (i << 6) + (q << 5);
      float acc = 0.0f;
#pragma unroll
      for (int kk = 0; kk < 32; kk += 4) {
        const float4 g4 = *(const float4*)(gr + kk);
        const float4 x4 = *(const float4*)&sm.x[(q << 5) + kk];
        acc += g4.x * x4.x + g4.y * x4.y + g4.z * x4.z + g4.w * x4.w;
      }
      acc += __shfl_down(acc, 1);
      if (q == 0) sm.rz[i] = acc + sm.s[i] - hb[i];
    }
    __syncthreads();
    if (tid < 64)
      sm.rxv[tid] = pb[tid] + Ab[tid] * sm.scal[SC_Y]
                  + sm.Vd[tid] + sm.Vd[64 + tid] + sm.Vd[128 + tid] + sm.Vd[192 + tid];
    __syncthreads();
    if (tid < 64) {  // ry
      float v = Ab[tid] * sm.x[tid];
      v = wred_sum(v);
      if (tid == 0) sm.scal[SC_RY] = v - bb;
    } else if (tid < 128) {  // mu
      const int l = tid - 64;
      float v = sm.s[l] * sm.z[l] + sm.s[l + 64] * sm.z[l + 64];
      v = wred_sum(v);
      if (l == 0) sm.scal[SC_MU] = v * (1.0f / 128.0f);
    } else if (tid < 256) {
      const int i = tid - 128;
      sm.dd[i] = sm.z[i] / sm.s[i];
    }
    __syncthreads();
    factor_S(sm, 0, tid);
    // affine predictor (rs = z)
    solve_kkt(sm, qreg, Gb, Ab, 1, sm.rxv, sm.z, 1, sm.rz, sm.scal[SC_RY],
              sm.dxa, sm.dsa, sm.dza, SC_DYA, 0, tid);
    if (tid < 64) {  // alpha_aff
      float m = __builtin_inff();
#pragma unroll
      for (int rep = 0; rep < 2; ++rep) {
        const int i = tid + 64 * rep;
        m = fminf(m, step_val(sm.z[i], sm.dza[i]));
        m = fminf(m, step_val(sm.s[i], sm.dsa[i]));
      }
      m = wred_min(m);
      if (tid == 0) sm.scal[SC_ALPHA] = 0.999f * fminf(m, 1.0f);
    }
    __syncthreads();
    {
      const float alpha = sm.scal[SC_ALPHA];
      if (tid < 64) {  // sigma -> mu_sig
        float v = 0.0f;
#pragma unroll
        for (int rep = 0; rep < 2; ++rep) {
          const int i = tid + 64 * rep;
          v += (sm.s[i] + alpha * sm.dsa[i]) * (sm.z[i] + alpha * sm.dza[i]);
        }
        v = wred_sum(v);
        if (tid == 0) {
          const float mu = sm.scal[SC_MU];
          const float r = v / (mu * 128.0f);
          sm.scal[SC_MUSIG] = -mu * r * r * r;
        }
      }
    }
    __syncthreads();
    if (tid < 128)  // non_zero (uses AFFINE dsa/dza; reuse rz buffer)
      sm.rz[tid] = (sm.scal[SC_MUSIG] + sm.dsa[tid] * sm.dza[tid]) / sm.s[tid];
    __syncthreads();
    // corrector: accumulates into dxa/dsa/dza/SC_DYA
    solve_kkt(sm, qreg, Gb, Ab, 0, nullptr, sm.rz, 0, nullptr, 0.0f,
              sm.dxa, sm.dsa, sm.dza, SC_DYA, 1, tid);
    if (tid < 64) {  // alpha on combined step
      float m = __builtin_inff();
#pragma unroll
      for (int rep = 0; rep < 2; ++rep) {
        const int i = tid + 64 * rep;
        m = fminf(m, step_val(sm.z[i], sm.dza[i]));
        m = fminf(m, step_val(sm.s[i], sm.dsa[i]));
      }
      m = wred_min(m);
      if (tid == 0) sm.scal[SC_ALPHA] = 0.999f * fminf(m, 1.0f);
    }
    __syncthreads();
    {
      const float a2 = sm.scal[SC_ALPHA];
      if (tid < 128) sm.s[tid] += a2 * sm.dsa[tid];
      else if (tid < 256) sm.z[tid - 128] += a2 * sm.dza[tid - 128];
    }
    if (tid < 64) sm.x[tid] += sm.scal[SC_ALPHA] * sm.dxa[tid];
    if (tid == 64) sm.scal[SC_Y] += sm.scal[SC_ALPHA] * sm.scal[SC_DYA];
    __syncthreads();
  }
  if (tid < 64) outg[((size_t)bId << 6) + tid] = sm.x[tid];
}

extern "C" void kernel_launch(void* const* d_in, const int* in_sizes, int n_in,
                              void* d_out, int out_size, void* d_ws, size_t ws_size,
                              hipStream_t stream) {
  (void)n_in; (void)d_ws; (void)ws_size; (void)out_size;
  const float* Q = (const float*)d_in[0];
  const float* p = (const float*)d_in[1];
  const float* A = (const float*)d_in[2];
  const float* b = (const float*)d_in[3];
  const float* G = (const float*)d_in[4];
  const float* h = (const float*)d_in[5];
  const int B = in_sizes[3];  // b has one element per batch
  optnet_kernel<<<B, NT, 0, stream>>>(Q, p, A, b, G, h, (float*)d_out);
}